// Round 5
// baseline (412.752 us; speedup 1.0000x reference)
//
#include <hip/hip_runtime.h>
#include <hip/hip_bf16.h>
#include <cstdint>
#include <cstddef>

#define BATCH 2
#define SEQ 2048
#define DMODEL 1024
#define DIN 2048
#define NH 32
#define HEADDIM 64
#define DSTATE 64
#define DCONV 4
#define CONV_DIM (DIN + 2 * DSTATE)          // 2176
#define DPROJ (2 * DIN + 2 * DSTATE + NH)    // 4256
#define MLP_INNER 4096
#define TOKENS (BATCH * SEQ)                 // 4096
#define EPS 1e-5f
#define Q 64
#define NCHUNK (SEQ / Q)                     // 32
#define NCH (BATCH * NCHUNK * NH)            // 2048 chunk-heads
#define LSTR 72                               // 144B rows (16B-aligned)
#define NPAD_IN 4352                          // DPROJ padded to 34*128

typedef __attribute__((ext_vector_type(8))) short short8;
typedef __attribute__((ext_vector_type(8))) __bf16 bf16x8;
typedef __attribute__((ext_vector_type(4))) float f32x4;

__device__ inline short f2bf(float f) {
    unsigned u = __builtin_bit_cast(unsigned, f);
    u = (u + 0x7FFFu + ((u >> 16) & 1u)) >> 16;
    return (short)u;
}
__device__ inline float bf2f(short s) {
    unsigned u = ((unsigned)(unsigned short)s) << 16;
    return __builtin_bit_cast(float, u);
}
__device__ inline float silu_f(float x) { return x / (1.f + __expf(-x)); }

__device__ inline bf16x8 ld_frag(const short* p) {
    short8 s = *(const short8*)p;
    return __builtin_bit_cast(bf16x8, s);
}

__device__ inline void glds16(const short* g, short* l) {
    __builtin_amdgcn_global_load_lds(
        (const __attribute__((address_space(1))) void*)g,
        (__attribute__((address_space(3))) void*)l, 16, 0, 0);
}

// ---------------- bf16 GEMM: m97 staging + dbuf + XCD swizzle (128x128) ----
// MODE 0: f32 C=AB; 1: bf16 C=silu(AB+bias); 2: f32 C=AB+bias+res; 3: f32 C=AB+res;
// MODE 4: bf16 C=AB.  KT=32 -> 4 blocks/CU.
// R4 lesson: this boring template beats the hand-scheduled 256^2 phased kernel
// at K=1024 (MLP-up: <=59 us here vs 62 us there). gemm256 deleted.
template <int MODE, int KT>
__global__ __launch_bounds__(256, (KT == 32) ? 4 : 2) void gemm_bf16_kernel(
    const short* __restrict__ A, const short* __restrict__ BT,
    void* __restrict__ Cout, const float* __restrict__ bias,
    const float* __restrict__ res, int M, int N, int K)
{
    const int tid  = threadIdx.x;
    const int wid  = tid >> 6;
    const int lane = tid & 63;
    const int lm   = lane & 15;
    const int lg   = lane >> 4;

    const int nb  = gridDim.x * gridDim.y;
    const int bid = blockIdx.y * gridDim.x + blockIdx.x;
    const int per = nb >> 3;
    const int nid = (bid & 7) * per + (bid >> 3);
    const int m0  = (nid / gridDim.x) * 128;
    const int n0  = (nid % gridDim.x) * 128;

    __shared__ __attribute__((aligned(16))) short Al0[128 * KT];
    __shared__ __attribute__((aligned(16))) short Al1[128 * KT];
    __shared__ __attribute__((aligned(16))) short Bl0[128 * KT];
    __shared__ __attribute__((aligned(16))) short Bl1[128 * KT];

    f32x4 acc[4][4];
#pragma unroll
    for (int i = 0; i < 4; ++i)
#pragma unroll
        for (int j = 0; j < 4; ++j) acc[i][j] = {0.f, 0.f, 0.f, 0.f};

    const int wm = (wid >> 1) * 64;
    const int wn = (wid & 1) * 64;

    constexpr int lpr = KT / 8;      // 16B blocks per row
    constexpr int rpi = 64 / lpr;    // rows per glds16 instr
    constexpr int nin = 32 / rpi;    // glds16 instrs per matrix per wave
    const int srow = lane / lpr;
    const int scb  = (lane % lpr) ^ (srow & (lpr - 1));   // swizzled source block
    const int scol = scb * 8;
    const short* Ag = A  + (size_t)(m0 + wid * 32 + srow) * K + scol;
    const short* Bg = BT + (size_t)(n0 + wid * 32 + srow) * K + scol;
    const int woff = wid * 32 * KT;

    const int niter = K / KT;
    {
#pragma unroll
        for (int j = 0; j < nin; ++j) {
            glds16(Ag + (size_t)j * rpi * K, Al0 + woff + j * 512);
            glds16(Bg + (size_t)j * rpi * K, Bl0 + woff + j * 512);
        }
    }

    for (int i = 0; i < niter; ++i) {
        __syncthreads();
        const short* Ac = (i & 1) ? Al1 : Al0;
        const short* Bc = (i & 1) ? Bl1 : Bl0;
        if (i + 1 < niter) {
            int kt = (i + 1) * KT;
            short* al = ((i & 1) ? Al0 : Al1) + woff;
            short* bl = ((i & 1) ? Bl0 : Bl1) + woff;
#pragma unroll
            for (int j = 0; j < nin; ++j) {
                glds16(Ag + kt + (size_t)j * rpi * K, al + j * 512);
                glds16(Bg + kt + (size_t)j * rpi * K, bl + j * 512);
            }
        }

#pragma unroll
        for (int sub = 0; sub < KT / 32; ++sub) {
            const int cb = sub * 4 + lg;
            bf16x8 af[4], bf[4];
#pragma unroll
            for (int ii = 0; ii < 4; ++ii) {
                int ar = wm + ii * 16 + lm;
                af[ii] = ld_frag(&Ac[ar * KT + ((cb ^ (ar & (lpr - 1))) * 8)]);
            }
#pragma unroll
            for (int j = 0; j < 4; ++j) {
                int br = wn + j * 16 + lm;
                bf[j] = ld_frag(&Bc[br * KT + ((cb ^ (br & (lpr - 1))) * 8)]);
            }
#pragma unroll
            for (int ii = 0; ii < 4; ++ii)
#pragma unroll
                for (int j = 0; j < 4; ++j)
                    acc[ii][j] = __builtin_amdgcn_mfma_f32_16x16x32_bf16(af[ii], bf[j], acc[ii][j], 0, 0, 0);
        }
    }

#pragma unroll
    for (int i = 0; i < 4; ++i) {
#pragma unroll
        for (int j = 0; j < 4; ++j) {
            int col = n0 + wn + j * 16 + lm;
            if (col >= N) continue;
            float bv = (MODE == 1 || MODE == 2) ? bias[col] : 0.f;
#pragma unroll
            for (int r = 0; r < 4; ++r) {
                int row = m0 + wm + i * 16 + lg * 4 + r;
                float v = acc[i][j][r];
                if (MODE == 1) {
                    ((short*)Cout)[(size_t)row * N + col] = f2bf(silu_f(v + bv));
                } else if (MODE == 4) {
                    ((short*)Cout)[(size_t)row * N + col] = f2bf(v);
                } else {
                    if (MODE == 2) v = v + bv + res[(size_t)row * N + col];
                    if (MODE == 3) v = v + res[(size_t)row * N + col];
                    ((float*)Cout)[(size_t)row * N + col] = v;
                }
            }
        }
    }
}

// ---------------- 64x128-tile bf16 GEMM, KT=64 (N=1024 GEMMs) --------------
// 256 thr = 4 waves; wave w: output rows 0..63 (fi=4), cols w*32 (fj=2).
// Grid (N/128) x (M/64) = 8 x 64 = 512 blocks -> 2 blk/CU (48KB LDS), so two
// blocks interleave and hide each other's barrier drains (R4: beat the
// 256-block 128^2 variant by ~7 us per GEMM).
// MODE 2: f32 C=AB+bias+res ; MODE 3: f32 C=AB+res.
template <int MODE>
__global__ __launch_bounds__(256, 2) void gemm64_kernel(
    const short* __restrict__ A, const short* __restrict__ BT,
    float* __restrict__ Cout, const float* __restrict__ bias,
    const float* __restrict__ res, int M, int N, int K)
{
    constexpr int KT = 64;
    const int tid  = threadIdx.x;
    const int wid  = tid >> 6;
    const int lane = tid & 63;
    const int lm   = lane & 15;
    const int lg   = lane >> 4;
    const int wn   = wid * 32;

    const int nb  = gridDim.x * gridDim.y;
    const int bid = blockIdx.y * gridDim.x + blockIdx.x;
    const int per = nb >> 3;
    const int nid = (bid & 7) * per + (bid >> 3);
    const int m0  = (nid / gridDim.x) * 64;
    const int n0  = (nid % gridDim.x) * 128;

    __shared__ __attribute__((aligned(16))) short Al0[64 * KT];
    __shared__ __attribute__((aligned(16))) short Al1[64 * KT];
    __shared__ __attribute__((aligned(16))) short Bl0[128 * KT];
    __shared__ __attribute__((aligned(16))) short Bl1[128 * KT];

    f32x4 acc[4][2];
#pragma unroll
    for (int i = 0; i < 4; ++i)
#pragma unroll
        for (int j = 0; j < 2; ++j) acc[i][j] = {0.f, 0.f, 0.f, 0.f};

    const int srow = lane >> 3;
    const int scb  = (lane & 7) ^ (srow & 7);
    const int scol = scb * 8;
    const short* Bg = BT + (size_t)(n0 + wid * 32 + srow) * K + scol;
    const short* Ag = A  + (size_t)(m0 + (wid & 1) * 32 + srow) * K + scol;
    const int woffB = wid * 32 * KT;
    const int woffA = (wid & 1) * 32 * KT;
    const bool doA = (wid < 2);

    const int niter = K / KT;
    {
#pragma unroll
        for (int j = 0; j < 4; ++j) {
            if (doA) glds16(Ag + (size_t)j * 8 * K, Al0 + woffA + j * 512);
            glds16(Bg + (size_t)j * 8 * K, Bl0 + woffB + j * 512);
        }
    }

    for (int i = 0; i < niter; ++i) {
        __syncthreads();
        const short* Ac = (i & 1) ? Al1 : Al0;
        const short* Bc = (i & 1) ? Bl1 : Bl0;
        if (i + 1 < niter) {
            int kt = (i + 1) * KT;
            short* al = ((i & 1) ? Al0 : Al1) + woffA;
            short* bl = ((i & 1) ? Bl0 : Bl1) + woffB;
#pragma unroll
            for (int j = 0; j < 4; ++j) {
                if (doA) glds16(Ag + kt + (size_t)j * 8 * K, al + j * 512);
                glds16(Bg + kt + (size_t)j * 8 * K, bl + j * 512);
            }
        }

#pragma unroll
        for (int sub = 0; sub < 2; ++sub) {
            const int cb = sub * 4 + lg;
            bf16x8 af[4], bf[2];
#pragma unroll
            for (int ii = 0; ii < 4; ++ii) {
                int ar = ii * 16 + lm;
                af[ii] = ld_frag(&Ac[ar * KT + ((cb ^ (ar & 7)) * 8)]);
            }
#pragma unroll
            for (int j = 0; j < 2; ++j) {
                int br = wn + j * 16 + lm;
                bf[j] = ld_frag(&Bc[br * KT + ((cb ^ (br & 7)) * 8)]);
            }
#pragma unroll
            for (int ii = 0; ii < 4; ++ii)
#pragma unroll
                for (int j = 0; j < 2; ++j)
                    acc[ii][j] = __builtin_amdgcn_mfma_f32_16x16x32_bf16(af[ii], bf[j], acc[ii][j], 0, 0, 0);
        }
    }

#pragma unroll
    for (int j = 0; j < 2; ++j) {
        int col = n0 + wn + j * 16 + lm;
        float bv = (MODE == 2) ? bias[col] : 0.f;
#pragma unroll
        for (int i = 0; i < 4; ++i) {
#pragma unroll
            for (int r = 0; r < 4; ++r) {
                int row = m0 + i * 16 + lg * 4 + r;
                float v = acc[i][j][r] + bv + res[(size_t)row * N + col];
                Cout[(size_t)row * N + col] = v;
            }
        }
    }
}

// ---------------- f32 -> bf16 convert ----------------
__global__ __launch_bounds__(256) void cvt_kernel(
    const float* __restrict__ src, short* __restrict__ dst, int n4)
{
    int i = (blockIdx.x * 256 + threadIdx.x);
    if (i >= n4) return;
    f32x4 v = *(const f32x4*)(src + (size_t)i * 4);
    short4 o;
    o.x = f2bf(v.x); o.y = f2bf(v.y); o.z = f2bf(v.z); o.w = f2bf(v.w);
    *(short4*)(dst + (size_t)i * 4) = o;
}

// ---------------- W [K][N] f32 -> WT [Npad][K] bf16 ----------------
__global__ __launch_bounds__(256) void transpose_kernel(
    const float* __restrict__ src, short* __restrict__ dst, int K, int N)
{
    __shared__ float t[32][33];
    int bx = blockIdx.x, by = blockIdx.y;
    int col = threadIdx.x & 31, row8 = threadIdx.x >> 5;
    int gn = bx * 32 + col;
#pragma unroll
    for (int r = 0; r < 4; ++r) {
        int gk = by * 32 + row8 + r * 8;
        t[row8 + r * 8][col] = (gn < N) ? src[(size_t)gk * N + gn] : 0.f;
    }
    __syncthreads();
#pragma unroll
    for (int r = 0; r < 4; ++r) {
        int n = bx * 32 + row8 + r * 8;
        dst[(size_t)n * K + by * 32 + col] = f2bf(t[col][row8 + r * 8]);
    }
}

// ---------------- depthwise causal conv (k=4) + bias + silu, bf16 in/out ----
#define CTOK 8
__global__ __launch_bounds__(256) void conv_kernel(
    const short* __restrict__ zx, const float* __restrict__ cw,
    const float* __restrict__ cb, short* __restrict__ xBCc)
{
    int c4 = blockIdx.y * 256 + threadIdx.x;
    if (c4 >= CONV_DIM / 4) return;
    int c  = c4 * 4;
    int m0 = blockIdx.x * CTOK;
    int l0 = m0 & (SEQ - 1);

    const short* base = zx + (size_t)m0 * DPROJ + DIN + c;
    f32x4 win[CTOK + 3];
#pragma unroll
    for (int j = 0; j < CTOK + 3; ++j) {
        int off = j - 3;
        if (l0 + off >= 0) {
            short4 sv = *(const short4*)(base + (ptrdiff_t)off * DPROJ);
            win[j] = {bf2f(sv.x), bf2f(sv.y), bf2f(sv.z), bf2f(sv.w)};
        } else {
            win[j] = {0.f, 0.f, 0.f, 0.f};
        }
    }
    f32x4 w0 = *(const f32x4*)(cw + (c + 0) * DCONV);
    f32x4 w1 = *(const f32x4*)(cw + (c + 1) * DCONV);
    f32x4 w2 = *(const f32x4*)(cw + (c + 2) * DCONV);
    f32x4 w3 = *(const f32x4*)(cw + (c + 3) * DCONV);
    f32x4 bb = *(const f32x4*)(cb + c);

    short* outp = xBCc + (size_t)m0 * CONV_DIM + c;
#pragma unroll
    for (int t = 0; t < CTOK; ++t) {
        f32x4 a = {bb.x, bb.y, bb.z, bb.w};
#pragma unroll
        for (int j = 0; j < DCONV; ++j) {
            f32x4 v = win[t + j];
            a.x += v.x * w0[j];
            a.y += v.y * w1[j];
            a.z += v.z * w2[j];
            a.w += v.w * w3[j];
        }
        short4 o;
        o.x = f2bf(silu_f(a.x)); o.y = f2bf(silu_f(a.y));
        o.z = f2bf(silu_f(a.z)); o.w = f2bf(silu_f(a.w));
        *(short4*)(outp + (size_t)t * CONV_DIM) = o;
    }
}

// ---------------- dt = softplus(dt_raw + bias); ldA = A * dt ----------------
__global__ __launch_bounds__(256) void dt_kernel(
    const short* __restrict__ zx, const float* __restrict__ dt_bias,
    const float* __restrict__ A_log, float* __restrict__ dtb, float* __restrict__ ldab)
{
    int idx = blockIdx.x * 256 + threadIdx.x;
    if (idx >= TOKENS * NH) return;
    int hh = idx & (NH - 1);
    int m  = idx >> 5;
    float v  = bf2f(zx[(size_t)m * DPROJ + DIN + CONV_DIM + hh]) + dt_bias[hh];
    float dt = (v > 20.f) ? v : log1pf(__expf(v));
    dtb[idx]  = dt;
    ldab[idx] = -__expf(A_log[hh]) * dt;
}

// ---------------- P1: intra-chunk SSD (bf16 xBCc) ----------------
__global__ __launch_bounds__(256) void chunk_kernel(
    const short* __restrict__ xBCc, const float* __restrict__ dtb,
    const float* __restrict__ ldab, float* __restrict__ ybuf,
    float* __restrict__ Sbuf, float* __restrict__ cumdecay)
{
    int bid = blockIdx.x;
    int h = bid & 31, c = (bid >> 5) & 31, b = bid >> 10;
    int m0 = b * SEQ + c * Q;
    int tid = threadIdx.x;
    int wid = tid >> 6, lane = tid & 63, lm = lane & 15, lg = lane >> 4;

    __shared__ __attribute__((aligned(16))) short Cc[64 * LSTR];
    __shared__ __attribute__((aligned(16))) short Bb[64 * LSTR];
    __shared__ __attribute__((aligned(16))) short BwT[64 * LSTR];
    __shared__ __attribute__((aligned(16))) short Xt[64 * LSTR];
    __shared__ __attribute__((aligned(16))) short Mm[64 * LSTR];
    __shared__ float Lc[64], dtv[64];

    if (tid < 64) {
        int s = tid;
        size_t ix = (size_t)(m0 + s) * NH + h;
        float ld = ldab[ix];
        float dt = dtb[ix];
        float v = ld;
#pragma unroll
        for (int off = 1; off < 64; off <<= 1) {
            float o = __shfl_up(v, off);
            if (s >= off) v += o;
        }
        Lc[s] = v;
        dtv[s] = dt;
        cumdecay[(size_t)bid * 64 + s] = __expf(v);
    }
    {
        int row = tid >> 2, c0 = (tid & 3) * 16;
        const short* pB = xBCc + (size_t)(m0 + row) * CONV_DIM + DIN;
#pragma unroll
        for (int u = 0; u < 2; ++u) {
            short8 vb = *(const short8*)(pB + c0 + 8 * u);
            short8 vc = *(const short8*)(pB + DSTATE + c0 + 8 * u);
            *(short8*)&Bb[row * LSTR + c0 + 8 * u] = vb;
            *(short8*)&Cc[row * LSTR + c0 + 8 * u] = vc;
        }
    }
    __syncthreads();
    {
        int s = tid >> 2, c0 = (tid & 3) * 16;
        float w = dtv[s];
        float w2 = __expf(Lc[63] - Lc[s]);
        const short* pX = xBCc + (size_t)(m0 + s) * CONV_DIM + h * HEADDIM;
#pragma unroll
        for (int u = 0; u < 4; ++u) {
            short4 v = *(const short4*)(pX + c0 + 4 * u);
            Xt[(c0 + 4 * u + 0) * LSTR + s] = f2bf(bf2f(v.x) * w);
            Xt[(c0 + 4 * u + 1) * LSTR + s] = f2bf(bf2f(v.y) * w);
            Xt[(c0 + 4 * u + 2) * LSTR + s] = f2bf(bf2f(v.z) * w);
            Xt[(c0 + 4 * u + 3) * LSTR + s] = f2bf(bf2f(v.w) * w);
            short4 sb = *(short4*)&Bb[s * LSTR + c0 + 4 * u];
            BwT[(c0 + 4 * u + 0) * LSTR + s] = f2bf(bf2f(sb.x) * w2);
            BwT[(c0 + 4 * u + 1) * LSTR + s] = f2bf(bf2f(sb.y) * w2);
            BwT[(c0 + 4 * u + 2) * LSTR + s] = f2bf(bf2f(sb.z) * w2);
            BwT[(c0 + 4 * u + 3) * LSTR + s] = f2bf(bf2f(sb.w) * w2);
        }
    }
    __syncthreads();

    {
        bf16x8 af[2];
#pragma unroll
        for (int kk = 0; kk < 2; ++kk)
            af[kk] = ld_frag(&Cc[(wid * 16 + lm) * LSTR + kk * 32 + lg * 8]);
#pragma unroll
        for (int j = 0; j < 4; ++j) {
            f32x4 acc = {0.f, 0.f, 0.f, 0.f};
#pragma unroll
            for (int kk = 0; kk < 2; ++kk) {
                bf16x8 bf = ld_frag(&Bb[(j * 16 + lm) * LSTR + kk * 32 + lg * 8]);
                acc = __builtin_amdgcn_mfma_f32_16x16x32_bf16(af[kk], bf, acc, 0, 0, 0);
            }
            int s = j * 16 + lm;
            float Ls = Lc[s];
#pragma unroll
            for (int r = 0; r < 4; ++r) {
                int t = wid * 16 + lg * 4 + r;
                float val = (s <= t) ? acc[r] * __expf(Lc[t] - Ls) : 0.f;
                Mm[t * LSTR + s] = f2bf(val);
            }
        }
    }
    __syncthreads();

    {
        bf16x8 am[2], aw[2];
#pragma unroll
        for (int kk = 0; kk < 2; ++kk) {
            am[kk] = ld_frag(&Mm[(wid * 16 + lm) * LSTR + kk * 32 + lg * 8]);
            aw[kk] = ld_frag(&BwT[(wid * 16 + lm) * LSTR + kk * 32 + lg * 8]);
        }
#pragma unroll
        for (int j = 0; j < 4; ++j) {
            f32x4 a1 = {0.f, 0.f, 0.f, 0.f};
            f32x4 a2 = {0.f, 0.f, 0.f, 0.f};
#pragma unroll
            for (int kk = 0; kk < 2; ++kk) {
                bf16x8 bx = ld_frag(&Xt[(j * 16 + lm) * LSTR + kk * 32 + lg * 8]);
                a1 = __builtin_amdgcn_mfma_f32_16x16x32_bf16(am[kk], bx, a1, 0, 0, 0);
                a2 = __builtin_amdgcn_mfma_f32_16x16x32_bf16(aw[kk], bx, a2, 0, 0, 0);
            }
            int p = j * 16 + lm;
#pragma unroll
            for (int r = 0; r < 4; ++r) {
                int t = wid * 16 + lg * 4 + r;
                ybuf[(size_t)(m0 + t) * DIN + h * HEADDIM + p] = a1[r];
                Sbuf[(size_t)bid * 4096 + t * 64 + p] = a2[r];
            }
        }
    }
}

// ---------------- P2: inter-chunk state recurrence (256 blocks + prefetch) --
__global__ __launch_bounds__(256) void state_kernel(
    float* __restrict__ SH, const float* __restrict__ cumdecay)
{
    int bh = blockIdx.x >> 2, st = blockIdx.x & 3;
    int b = bh >> 5, h = bh & 31;
    size_t off = (size_t)st * 1024 + (size_t)threadIdx.x * 4;

    f32x4 H = {0.f, 0.f, 0.f, 0.f};
    int cid = b * NCHUNK * NH + h;
    f32x4 s_next = *(const f32x4*)(SH + (size_t)cid * 4096 + off);
    float cd_next = cumdecay[(size_t)cid * 64 + 63];

    for (int c = 0; c < NCHUNK; ++c) {
        f32x4 s = s_next;
        float cd = cd_next;
        size_t base = (size_t)cid * 4096 + off;
        if (c + 1 < NCHUNK) {
            int cid1 = cid + NH;
            s_next = *(const f32x4*)(SH + (size_t)cid1 * 4096 + off);
            cd_next = cumdecay[(size_t)cid1 * 64 + 63];
        }
        *(f32x4*)(SH + base) = H;
        H.x = cd * H.x + s.x;
        H.y = cd * H.y + s.y;
        H.z = cd * H.z + s.z;
        H.w = cd * H.w + s.w;
        cid += NH;
    }
}

// ---------------- P3: y += exp(Lc_t) * C_t @ H_in ----------------
__global__ __launch_bounds__(256) void inter_kernel(
    const short* __restrict__ xBCc, const float* __restrict__ Hin,
    const float* __restrict__ cumdecay, float* __restrict__ ybuf)
{
    int bid = blockIdx.x;
    int h = bid & 31, c = (bid >> 5) & 31, b = bid >> 10;
    int m0 = b * SEQ + c * Q;
    int tid = threadIdx.x;
    int wid = tid >> 6, lane = tid & 63, lm = lane & 15, lg = lane >> 4;

    __shared__ __attribute__((aligned(16))) short Cc[64 * LSTR];
    __shared__ __attribute__((aligned(16))) short HT[64 * LSTR];
    __shared__ float eLc[64];

    if (tid < 64) eLc[tid] = cumdecay[(size_t)bid * 64 + tid];
    {
        int row = tid >> 2, c0 = (tid & 3) * 16;
        const short* pC = xBCc + (size_t)(m0 + row) * CONV_DIM + DIN + DSTATE;
#pragma unroll
        for (int u = 0; u < 2; ++u) {
            short8 vc = *(const short8*)(pC + c0 + 8 * u);
            *(short8*)&Cc[row * LSTR + c0 + 8 * u] = vc;
        }
        const float* pH = Hin + (size_t)bid * 4096 + row * 64;
#pragma unroll
        for (int u = 0; u < 4; ++u) {
            f32x4 vh = *(const f32x4*)(pH + c0 + 4 * u);
            HT[(c0 + 4 * u + 0) * LSTR + row] = f2bf(vh.x);
            HT[(c0 + 4 * u + 1) * LSTR + row] = f2bf(vh.y);
            HT[(c0 + 4 * u + 2) * LSTR + row] = f2bf(vh.z);
            HT[(c0 + 4 * u + 3) * LSTR + row] = f2bf(vh.w);
        }
    }
    __syncthreads();

    bf16x8 af[2];
#pragma unroll
    for (int kk = 0; kk < 2; ++kk)
        af[kk] = ld_frag(&Cc[(wid * 16 + lm) * LSTR + kk * 32 + lg * 8]);
#pragma unroll
    for (int j = 0; j < 4; ++j) {
        f32x4 acc = {0.f, 0.f, 0.f, 0.f};
#pragma unroll
        for (int kk = 0; kk < 2; ++kk) {
            bf16x8 bh_ = ld_frag(&HT[(j * 16 + lm) * LSTR + kk * 32 + lg * 8]);
            acc = __builtin_amdgcn_mfma_f32_16x16x32_bf16(af[kk], bh_, acc, 0, 0, 0);
        }
        int p = j * 16 + lm;
#pragma unroll
        for (int r = 0; r < 4; ++r) {
            int t = wid * 16 + lg * 4 + r;
            size_t ya = (size_t)(m0 + t) * DIN + h * HEADDIM + p;
            ybuf[ya] += eLc[t] * acc[r];
        }
    }
}

// ---------------- ybf = bf16(rmsnorm((y + D*x) * silu(z), norm_w)) ----------
// G13: thread owns 8 contiguous elements -> short8/f32x4 loads, short8 store.
__global__ __launch_bounds__(256) void norm1_kernel(
    const short* __restrict__ zx, const short* __restrict__ xBCc,
    const float* __restrict__ Dp, const float* __restrict__ y,
    short* __restrict__ ybf, const float* __restrict__ w)
{
    int m = blockIdx.x;
    int t = threadIdx.x;
    int i0 = t * 8;
    const short8 zv = *(const short8*)(zx + (size_t)m * DPROJ + i0);
    const short8 xv = *(const short8*)(xBCc + (size_t)m * CONV_DIM + i0);
    const float* yr = y + (size_t)m * DIN + i0;
    f32x4 y0 = *(const f32x4*)(yr);
    f32x4 y1 = *(const f32x4*)(yr + 4);
    float Dv = Dp[i0 >> 6];           // 8 elems span one head (HEADDIM=64)

    float vals[8];
    float ss = 0.f;
#pragma unroll
    for (int j = 0; j < 8; ++j) {
        float yj = (j < 4) ? y0[j] : y1[j - 4];
        float v = (yj + Dv * bf2f(xv[j])) * silu_f(bf2f(zv[j]));
        vals[j] = v;
        ss += v * v;
    }
#pragma unroll
    for (int o = 32; o >= 1; o >>= 1) ss += __shfl_xor(ss, o);
    __shared__ float wsum[4];
    if ((t & 63) == 0) wsum[t >> 6] = ss;
    __syncthreads();
    float tot = wsum[0] + wsum[1] + wsum[2] + wsum[3];
    float scale = rsqrtf(tot / (float)DIN + EPS);

    f32x4 w0 = *(const f32x4*)(w + i0);
    f32x4 w1 = *(const f32x4*)(w + i0 + 4);
    short8 ov;
#pragma unroll
    for (int j = 0; j < 8; ++j) {
        float wj = (j < 4) ? w0[j] : w1[j - 4];
        ov[j] = f2bf(vals[j] * scale * wj);
    }
    *(short8*)(ybf + (size_t)m * DIN + i0) = ov;
}

// ---------------- hnbf = bf16(rmsnorm(h, rms_w)) ----------------
__global__ __launch_bounds__(256) void norm2_kernel(
    const float* __restrict__ hb, short* __restrict__ hnbf, const float* __restrict__ w)
{
    int m = blockIdx.x;
    int t = threadIdx.x;
    int i0 = t * 4;
    f32x4 hv = *(const f32x4*)(hb + (size_t)m * DMODEL + i0);
    float ss = hv.x * hv.x + hv.y * hv.y + hv.z * hv.z + hv.w * hv.w;
#pragma unroll
    for (int o = 32; o >= 1; o >>= 1) ss += __shfl_xor(ss, o);
    __shared__ float wsum[4];
    if ((t & 63) == 0) wsum[t >> 6] = ss;
    __syncthreads();
    float tot = wsum[0] + wsum[1] + wsum[2] + wsum[3];
    float scale = rsqrtf(tot / (float)DMODEL + EPS);
    f32x4 wv = *(const f32x4*)(w + i0);
    short4 ov;
    ov.x = f2bf(hv.x * scale * wv.x);
    ov.y = f2bf(hv.y * scale * wv.y);
    ov.z = f2bf(hv.z * scale * wv.z);
    ov.w = f2bf(hv.w * scale * wv.w);
    *(short4*)(hnbf + (size_t)m * DMODEL + i0) = ov;
}

extern "C" void kernel_launch(void* const* d_in, const int* in_sizes, int n_in,
                              void* d_out, int out_size, void* d_ws, size_t ws_size,
                              hipStream_t stream) {
    const float* x       = (const float*)d_in[0];
    const float* W_in    = (const float*)d_in[1];
    const float* conv_w  = (const float*)d_in[2];
    const float* conv_b  = (const float*)d_in[3];
    const float* dt_bias = (const float*)d_in[4];
    const float* A_log   = (const float*)d_in[5];
    const float* D_param = (const float*)d_in[6];
    const float* norm_w  = (const float*)d_in[7];
    const float* W_out   = (const float*)d_in[8];
    const float* rms_w   = (const float*)d_in[9];
    const float* mlp_w1  = (const float*)d_in[10];
    const float* mlp_b1  = (const float*)d_in[11];
    const float* mlp_w2  = (const float*)d_in[12];
    const float* mlp_b2  = (const float*)d_in[13];
    float* out = (float*)d_out;

    float* ws       = (float*)d_ws;
    float* zxf      = ws;                                  // holds bf16 zx
    float* xBCf     = zxf + (size_t)TOKENS * DPROJ;        // holds bf16 xBCc
    float* dtb      = xBCf + (size_t)TOKENS * CONV_DIM;
    float* ldab     = dtb + (size_t)TOKENS * NH;
    float* cumdecay = ldab + (size_t)TOKENS * NH;
    float* ybuf     = cumdecay + (size_t)TOKENS * NH;
    float* SH       = ybuf + (size_t)TOKENS * DIN;
    float* bfarea   = SH + (size_t)NCH * 4096;

    short* zxb   = (short*)zxf;
    short* xBCb  = (short*)xBCf;
    short* xbf   = (short*)ybuf;
    short* midbf = (short*)ybuf;
    float* hbuf  = SH;
    short* hnbf  = (short*)(SH + (size_t)TOKENS * DMODEL);

    short* ybf   = (short*)bfarea;
    short* WinT  = ybf + (size_t)TOKENS * DIN;
    short* WoutT = WinT + (size_t)NPAD_IN * DMODEL;
    short* w1T   = WoutT + (size_t)DMODEL * DIN;
    short* w2T   = w1T + (size_t)MLP_INNER * DMODEL;

    dim3 blk(256);

    // 0. conversions / weight transposes
    cvt_kernel<<<dim3(TOKENS * DMODEL / 4 / 256), blk, 0, stream>>>(x, xbf, TOKENS * DMODEL / 4);
    transpose_kernel<<<dim3(NPAD_IN / 32, DMODEL / 32), blk, 0, stream>>>(W_in, WinT, DMODEL, DPROJ);
    transpose_kernel<<<dim3(DMODEL / 32, DIN / 32), blk, 0, stream>>>(W_out, WoutT, DIN, DMODEL);
    transpose_kernel<<<dim3(MLP_INNER / 32, DMODEL / 32), blk, 0, stream>>>(mlp_w1, w1T, DMODEL, MLP_INNER);
    transpose_kernel<<<dim3(DMODEL / 32, MLP_INNER / 32), blk, 0, stream>>>(mlp_w2, w2T, MLP_INNER, DMODEL);

    // 1. zx = bf16(x @ W_in)  (1088 blocks -> 128^2 KT=32 path, 4 blk/CU)
    gemm_bf16_kernel<4, 32><<<dim3(NPAD_IN / 128, TOKENS / 128), blk, 0, stream>>>(
        xbf, WinT, zxb, nullptr, nullptr, TOKENS, DPROJ, DMODEL);
    // 2. conv + bias + silu (bf16 in/out, token-blocked)
    conv_kernel<<<dim3(TOKENS / CTOK, (CONV_DIM / 4 + 255) / 256), blk, 0, stream>>>(
        zxb, conv_w, conv_b, xBCb);
    // 3. dt / ldA
    dt_kernel<<<dim3(TOKENS * NH / 256), blk, 0, stream>>>(zxb, dt_bias, A_log, dtb, ldab);
    // 4. SSD
    chunk_kernel<<<dim3(NCH), blk, 0, stream>>>(xBCb, dtb, ldab, ybuf, SH, cumdecay);
    state_kernel<<<dim3(BATCH * NH * 4), blk, 0, stream>>>(SH, cumdecay);
    inter_kernel<<<dim3(NCH), blk, 0, stream>>>(xBCb, SH, cumdecay, ybuf);
    // 5. ybf = bf16(rmsnorm((y + D*x) * silu(z)))
    norm1_kernel<<<dim3(TOKENS), blk, 0, stream>>>(zxb, xBCb, D_param, ybuf, ybf, norm_w);
    // 6. h = x + ybf @ W_out  (64x128 tiles: 8 x 64 = 512 blocks, 2 blk/CU)
    gemm64_kernel<3><<<dim3(DMODEL / 128, TOKENS / 64), blk, 0, stream>>>(
        ybf, WoutT, hbuf, nullptr, x, TOKENS, DMODEL, DIN);
    // 7. hnbf = bf16(rmsnorm(h))
    norm2_kernel<<<dim3(TOKENS), blk, 0, stream>>>(hbuf, hnbf, rms_w);
    // 8. midbf = bf16(silu(hnbf @ mlp_w1 + b1))  (1024 blocks -> 128^2 KT=32, 4 blk/CU)
    gemm_bf16_kernel<1, 32><<<dim3(MLP_INNER / 128, TOKENS / 128), blk, 0, stream>>>(
        hnbf, w1T, midbf, mlp_b1, nullptr, TOKENS, MLP_INNER, DMODEL);
    // 9. out = h + midbf @ mlp_w2 + b2  (64x128 tiles: 512 blocks, 2 blk/CU)
    gemm64_kernel<2><<<dim3(DMODEL / 128, TOKENS / 64), blk, 0, stream>>>(
        midbf, w2T, out, mlp_b2, hbuf, TOKENS, DMODEL, MLP_INNER);
}

// Round 6
// 408.902 us; speedup vs baseline: 1.0094x; 1.0094x over previous
//
#include <hip/hip_runtime.h>
#include <hip/hip_bf16.h>
#include <cstdint>
#include <cstddef>

#define BATCH 2
#define SEQ 2048
#define DMODEL 1024
#define DIN 2048
#define NH 32
#define HEADDIM 64
#define DSTATE 64
#define DCONV 4
#define CONV_DIM (DIN + 2 * DSTATE)          // 2176
#define DPROJ (2 * DIN + 2 * DSTATE + NH)    // 4256
#define MLP_INNER 4096
#define TOKENS (BATCH * SEQ)                 // 4096
#define EPS 1e-5f
#define Q 64
#define NCHUNK (SEQ / Q)                     // 32
#define NCH (BATCH * NCHUNK * NH)            // 2048 chunk-heads
#define LSTR 72                               // 144B rows (16B-aligned)
#define NPAD_IN 4352                          // DPROJ padded to 34*128

typedef __attribute__((ext_vector_type(8))) short short8;
typedef __attribute__((ext_vector_type(8))) __bf16 bf16x8;
typedef __attribute__((ext_vector_type(4))) float f32x4;

__device__ inline short f2bf(float f) {
    unsigned u = __builtin_bit_cast(unsigned, f);
    u = (u + 0x7FFFu + ((u >> 16) & 1u)) >> 16;
    return (short)u;
}
__device__ inline float bf2f(short s) {
    unsigned u = ((unsigned)(unsigned short)s) << 16;
    return __builtin_bit_cast(float, u);
}
__device__ inline float silu_f(float x) { return x / (1.f + __expf(-x)); }

__device__ inline bf16x8 ld_frag(const short* p) {
    short8 s = *(const short8*)p;
    return __builtin_bit_cast(bf16x8, s);
}

__device__ inline void glds16(const short* g, short* l) {
    __builtin_amdgcn_global_load_lds(
        (const __attribute__((address_space(1))) void*)g,
        (__attribute__((address_space(3))) void*)l, 16, 0, 0);
}

// ---------------- 64x128-tile bf16 GEMM, KT=64 (ALL four big GEMMs) --------
// 256 thr = 4 waves; wave w: output rows 0..63 (fi=4), cols w*32+{0,16} (fj=2).
// Grid (N/128) x (M/64) blocks -> 2 blk/CU (48KB LDS): two co-resident blocks
// hide each other's 2-barrier K-step drains (R4 evidence: this geometry beat
// the 128^2 paths on the N=1024 GEMMs; R5 showed 128^2/KT32 stuck at 60 us
// with 4.45M LDS bank conflicts -- KT=64's 8-slot XOR has 0).
// MODE 1: bf16 C=silu(AB+bias) [guard col<N] ; MODE 2: f32 C=AB+bias+res ;
// MODE 3: f32 C=AB+res ; MODE 4: bf16 C=AB [guard col<N].
template <int MODE>
__global__ __launch_bounds__(256, 2) void gemm64_kernel(
    const short* __restrict__ A, const short* __restrict__ BT,
    void* __restrict__ Cout, const float* __restrict__ bias,
    const float* __restrict__ res, int M, int N, int K)
{
    constexpr int KT = 64;
    const int tid  = threadIdx.x;
    const int wid  = tid >> 6;
    const int lane = tid & 63;
    const int lm   = lane & 15;
    const int lg   = lane >> 4;
    const int wn   = wid * 32;

    const int nb  = gridDim.x * gridDim.y;
    const int bid = blockIdx.y * gridDim.x + blockIdx.x;
    const int per = nb >> 3;
    const int nid = (bid & 7) * per + (bid >> 3);
    const int m0  = (nid / gridDim.x) * 64;
    const int n0  = (nid % gridDim.x) * 128;

    __shared__ __attribute__((aligned(16))) short Al0[64 * KT];
    __shared__ __attribute__((aligned(16))) short Al1[64 * KT];
    __shared__ __attribute__((aligned(16))) short Bl0[128 * KT];
    __shared__ __attribute__((aligned(16))) short Bl1[128 * KT];

    f32x4 acc[4][2];
#pragma unroll
    for (int i = 0; i < 4; ++i)
#pragma unroll
        for (int j = 0; j < 2; ++j) acc[i][j] = {0.f, 0.f, 0.f, 0.f};

    // staging: 8 16B chunks/row, 8 rows per glds16; XOR swizzle via source.
    const int srow = lane >> 3;
    const int scb  = (lane & 7) ^ (srow & 7);
    const int scol = scb * 8;
    const short* Bg = BT + (size_t)(n0 + wid * 32 + srow) * K + scol;
    const short* Ag = A  + (size_t)(m0 + (wid & 1) * 32 + srow) * K + scol;
    const int woffB = wid * 32 * KT;
    const int woffA = (wid & 1) * 32 * KT;
    const bool doA = (wid < 2);

    const int niter = K / KT;
    {
#pragma unroll
        for (int j = 0; j < 4; ++j) {
            if (doA) glds16(Ag + (size_t)j * 8 * K, Al0 + woffA + j * 512);
            glds16(Bg + (size_t)j * 8 * K, Bl0 + woffB + j * 512);
        }
    }

    for (int i = 0; i < niter; ++i) {
        __syncthreads();
        const short* Ac = (i & 1) ? Al1 : Al0;
        const short* Bc = (i & 1) ? Bl1 : Bl0;
        if (i + 1 < niter) {
            int kt = (i + 1) * KT;
            short* al = ((i & 1) ? Al0 : Al1) + woffA;
            short* bl = ((i & 1) ? Bl0 : Bl1) + woffB;
#pragma unroll
            for (int j = 0; j < 4; ++j) {
                if (doA) glds16(Ag + kt + (size_t)j * 8 * K, al + j * 512);
                glds16(Bg + kt + (size_t)j * 8 * K, bl + j * 512);
            }
        }

#pragma unroll
        for (int sub = 0; sub < 2; ++sub) {
            const int cb = sub * 4 + lg;
            bf16x8 af[4], bf[2];
#pragma unroll
            for (int ii = 0; ii < 4; ++ii) {
                int ar = ii * 16 + lm;
                af[ii] = ld_frag(&Ac[ar * KT + ((cb ^ (ar & 7)) * 8)]);
            }
#pragma unroll
            for (int j = 0; j < 2; ++j) {
                int br = wn + j * 16 + lm;
                bf[j] = ld_frag(&Bc[br * KT + ((cb ^ (br & 7)) * 8)]);
            }
#pragma unroll
            for (int ii = 0; ii < 4; ++ii)
#pragma unroll
                for (int j = 0; j < 2; ++j)
                    acc[ii][j] = __builtin_amdgcn_mfma_f32_16x16x32_bf16(af[ii], bf[j], acc[ii][j], 0, 0, 0);
        }
    }

#pragma unroll
    for (int j = 0; j < 2; ++j) {
        int col = n0 + wn + j * 16 + lm;
        if ((MODE == 1 || MODE == 4) && col >= N) continue;   // padded-N guard
        float bv = (MODE == 1 || MODE == 2) ? bias[col] : 0.f;
#pragma unroll
        for (int i = 0; i < 4; ++i) {
#pragma unroll
            for (int r = 0; r < 4; ++r) {
                int row = m0 + i * 16 + lg * 4 + r;
                float v = acc[i][j][r];
                if (MODE == 1) {
                    ((short*)Cout)[(size_t)row * N + col] = f2bf(silu_f(v + bv));
                } else if (MODE == 4) {
                    ((short*)Cout)[(size_t)row * N + col] = f2bf(v);
                } else {
                    v += bv + res[(size_t)row * N + col];
                    ((float*)Cout)[(size_t)row * N + col] = v;
                }
            }
        }
    }
}

// ---------------- f32 -> bf16 convert ----------------
__global__ __launch_bounds__(256) void cvt_kernel(
    const float* __restrict__ src, short* __restrict__ dst, int n4)
{
    int i = (blockIdx.x * 256 + threadIdx.x);
    if (i >= n4) return;
    f32x4 v = *(const f32x4*)(src + (size_t)i * 4);
    short4 o;
    o.x = f2bf(v.x); o.y = f2bf(v.y); o.z = f2bf(v.z); o.w = f2bf(v.w);
    *(short4*)(dst + (size_t)i * 4) = o;
}

// ---------------- W [K][N] f32 -> WT [Npad][K] bf16 ----------------
__global__ __launch_bounds__(256) void transpose_kernel(
    const float* __restrict__ src, short* __restrict__ dst, int K, int N)
{
    __shared__ float t[32][33];
    int bx = blockIdx.x, by = blockIdx.y;
    int col = threadIdx.x & 31, row8 = threadIdx.x >> 5;
    int gn = bx * 32 + col;
#pragma unroll
    for (int r = 0; r < 4; ++r) {
        int gk = by * 32 + row8 + r * 8;
        t[row8 + r * 8][col] = (gn < N) ? src[(size_t)gk * N + gn] : 0.f;
    }
    __syncthreads();
#pragma unroll
    for (int r = 0; r < 4; ++r) {
        int n = bx * 32 + row8 + r * 8;
        dst[(size_t)n * K + by * 32 + col] = f2bf(t[col][row8 + r * 8]);
    }
}

// ---------------- depthwise causal conv (k=4) + bias + silu, bf16 in/out ----
#define CTOK 8
__global__ __launch_bounds__(256) void conv_kernel(
    const short* __restrict__ zx, const float* __restrict__ cw,
    const float* __restrict__ cb, short* __restrict__ xBCc)
{
    int c4 = blockIdx.y * 256 + threadIdx.x;
    if (c4 >= CONV_DIM / 4) return;
    int c  = c4 * 4;
    int m0 = blockIdx.x * CTOK;
    int l0 = m0 & (SEQ - 1);

    const short* base = zx + (size_t)m0 * DPROJ + DIN + c;
    f32x4 win[CTOK + 3];
#pragma unroll
    for (int j = 0; j < CTOK + 3; ++j) {
        int off = j - 3;
        if (l0 + off >= 0) {
            short4 sv = *(const short4*)(base + (ptrdiff_t)off * DPROJ);
            win[j] = {bf2f(sv.x), bf2f(sv.y), bf2f(sv.z), bf2f(sv.w)};
        } else {
            win[j] = {0.f, 0.f, 0.f, 0.f};
        }
    }
    f32x4 w0 = *(const f32x4*)(cw + (c + 0) * DCONV);
    f32x4 w1 = *(const f32x4*)(cw + (c + 1) * DCONV);
    f32x4 w2 = *(const f32x4*)(cw + (c + 2) * DCONV);
    f32x4 w3 = *(const f32x4*)(cw + (c + 3) * DCONV);
    f32x4 bb = *(const f32x4*)(cb + c);

    short* outp = xBCc + (size_t)m0 * CONV_DIM + c;
#pragma unroll
    for (int t = 0; t < CTOK; ++t) {
        f32x4 a = {bb.x, bb.y, bb.z, bb.w};
#pragma unroll
        for (int j = 0; j < DCONV; ++j) {
            f32x4 v = win[t + j];
            a.x += v.x * w0[j];
            a.y += v.y * w1[j];
            a.z += v.z * w2[j];
            a.w += v.w * w3[j];
        }
        short4 o;
        o.x = f2bf(silu_f(a.x)); o.y = f2bf(silu_f(a.y));
        o.z = f2bf(silu_f(a.z)); o.w = f2bf(silu_f(a.w));
        *(short4*)(outp + (size_t)t * CONV_DIM) = o;
    }
}

// ---------------- dt = softplus(dt_raw + bias); ldA = A * dt ----------------
__global__ __launch_bounds__(256) void dt_kernel(
    const short* __restrict__ zx, const float* __restrict__ dt_bias,
    const float* __restrict__ A_log, float* __restrict__ dtb, float* __restrict__ ldab)
{
    int idx = blockIdx.x * 256 + threadIdx.x;
    if (idx >= TOKENS * NH) return;
    int hh = idx & (NH - 1);
    int m  = idx >> 5;
    float v  = bf2f(zx[(size_t)m * DPROJ + DIN + CONV_DIM + hh]) + dt_bias[hh];
    float dt = (v > 20.f) ? v : log1pf(__expf(v));
    dtb[idx]  = dt;
    ldab[idx] = -__expf(A_log[hh]) * dt;
}

// ---------------- P1: intra-chunk SSD (bf16 xBCc) ----------------
__global__ __launch_bounds__(256) void chunk_kernel(
    const short* __restrict__ xBCc, const float* __restrict__ dtb,
    const float* __restrict__ ldab, float* __restrict__ ybuf,
    float* __restrict__ Sbuf, float* __restrict__ cumdecay)
{
    int bid = blockIdx.x;
    int h = bid & 31, c = (bid >> 5) & 31, b = bid >> 10;
    int m0 = b * SEQ + c * Q;
    int tid = threadIdx.x;
    int wid = tid >> 6, lane = tid & 63, lm = lane & 15, lg = lane >> 4;

    __shared__ __attribute__((aligned(16))) short Cc[64 * LSTR];
    __shared__ __attribute__((aligned(16))) short Bb[64 * LSTR];
    __shared__ __attribute__((aligned(16))) short BwT[64 * LSTR];
    __shared__ __attribute__((aligned(16))) short Xt[64 * LSTR];
    __shared__ __attribute__((aligned(16))) short Mm[64 * LSTR];
    __shared__ float Lc[64], dtv[64];

    if (tid < 64) {
        int s = tid;
        size_t ix = (size_t)(m0 + s) * NH + h;
        float ld = ldab[ix];
        float dt = dtb[ix];
        float v = ld;
#pragma unroll
        for (int off = 1; off < 64; off <<= 1) {
            float o = __shfl_up(v, off);
            if (s >= off) v += o;
        }
        Lc[s] = v;
        dtv[s] = dt;
        cumdecay[(size_t)bid * 64 + s] = __expf(v);
    }
    {
        int row = tid >> 2, c0 = (tid & 3) * 16;
        const short* pB = xBCc + (size_t)(m0 + row) * CONV_DIM + DIN;
#pragma unroll
        for (int u = 0; u < 2; ++u) {
            short8 vb = *(const short8*)(pB + c0 + 8 * u);
            short8 vc = *(const short8*)(pB + DSTATE + c0 + 8 * u);
            *(short8*)&Bb[row * LSTR + c0 + 8 * u] = vb;
            *(short8*)&Cc[row * LSTR + c0 + 8 * u] = vc;
        }
    }
    __syncthreads();
    {
        int s = tid >> 2, c0 = (tid & 3) * 16;
        float w = dtv[s];
        float w2 = __expf(Lc[63] - Lc[s]);
        const short* pX = xBCc + (size_t)(m0 + s) * CONV_DIM + h * HEADDIM;
#pragma unroll
        for (int u = 0; u < 4; ++u) {
            short4 v = *(const short4*)(pX + c0 + 4 * u);
            Xt[(c0 + 4 * u + 0) * LSTR + s] = f2bf(bf2f(v.x) * w);
            Xt[(c0 + 4 * u + 1) * LSTR + s] = f2bf(bf2f(v.y) * w);
            Xt[(c0 + 4 * u + 2) * LSTR + s] = f2bf(bf2f(v.z) * w);
            Xt[(c0 + 4 * u + 3) * LSTR + s] = f2bf(bf2f(v.w) * w);
            short4 sb = *(short4*)&Bb[s * LSTR + c0 + 4 * u];
            BwT[(c0 + 4 * u + 0) * LSTR + s] = f2bf(bf2f(sb.x) * w2);
            BwT[(c0 + 4 * u + 1) * LSTR + s] = f2bf(bf2f(sb.y) * w2);
            BwT[(c0 + 4 * u + 2) * LSTR + s] = f2bf(bf2f(sb.z) * w2);
            BwT[(c0 + 4 * u + 3) * LSTR + s] = f2bf(bf2f(sb.w) * w2);
        }
    }
    __syncthreads();

    {
        bf16x8 af[2];
#pragma unroll
        for (int kk = 0; kk < 2; ++kk)
            af[kk] = ld_frag(&Cc[(wid * 16 + lm) * LSTR + kk * 32 + lg * 8]);
#pragma unroll
        for (int j = 0; j < 4; ++j) {
            f32x4 acc = {0.f, 0.f, 0.f, 0.f};
#pragma unroll
            for (int kk = 0; kk < 2; ++kk) {
                bf16x8 bf = ld_frag(&Bb[(j * 16 + lm) * LSTR + kk * 32 + lg * 8]);
                acc = __builtin_amdgcn_mfma_f32_16x16x32_bf16(af[kk], bf, acc, 0, 0, 0);
            }
            int s = j * 16 + lm;
            float Ls = Lc[s];
#pragma unroll
            for (int r = 0; r < 4; ++r) {
                int t = wid * 16 + lg * 4 + r;
                float val = (s <= t) ? acc[r] * __expf(Lc[t] - Ls) : 0.f;
                Mm[t * LSTR + s] = f2bf(val);
            }
        }
    }
    __syncthreads();

    {
        bf16x8 am[2], aw[2];
#pragma unroll
        for (int kk = 0; kk < 2; ++kk) {
            am[kk] = ld_frag(&Mm[(wid * 16 + lm) * LSTR + kk * 32 + lg * 8]);
            aw[kk] = ld_frag(&BwT[(wid * 16 + lm) * LSTR + kk * 32 + lg * 8]);
        }
#pragma unroll
        for (int j = 0; j < 4; ++j) {
            f32x4 a1 = {0.f, 0.f, 0.f, 0.f};
            f32x4 a2 = {0.f, 0.f, 0.f, 0.f};
#pragma unroll
            for (int kk = 0; kk < 2; ++kk) {
                bf16x8 bx = ld_frag(&Xt[(j * 16 + lm) * LSTR + kk * 32 + lg * 8]);
                a1 = __builtin_amdgcn_mfma_f32_16x16x32_bf16(am[kk], bx, a1, 0, 0, 0);
                a2 = __builtin_amdgcn_mfma_f32_16x16x32_bf16(aw[kk], bx, a2, 0, 0, 0);
            }
            int p = j * 16 + lm;
#pragma unroll
            for (int r = 0; r < 4; ++r) {
                int t = wid * 16 + lg * 4 + r;
                ybuf[(size_t)(m0 + t) * DIN + h * HEADDIM + p] = a1[r];
                Sbuf[(size_t)bid * 4096 + t * 64 + p] = a2[r];
            }
        }
    }
}

// ---------------- P2: inter-chunk state recurrence (256 blocks + prefetch) --
__global__ __launch_bounds__(256) void state_kernel(
    float* __restrict__ SH, const float* __restrict__ cumdecay)
{
    int bh = blockIdx.x >> 2, st = blockIdx.x & 3;
    int b = bh >> 5, h = bh & 31;
    size_t off = (size_t)st * 1024 + (size_t)threadIdx.x * 4;

    f32x4 H = {0.f, 0.f, 0.f, 0.f};
    int cid = b * NCHUNK * NH + h;
    f32x4 s_next = *(const f32x4*)(SH + (size_t)cid * 4096 + off);
    float cd_next = cumdecay[(size_t)cid * 64 + 63];

    for (int c = 0; c < NCHUNK; ++c) {
        f32x4 s = s_next;
        float cd = cd_next;
        size_t base = (size_t)cid * 4096 + off;
        if (c + 1 < NCHUNK) {
            int cid1 = cid + NH;
            s_next = *(const f32x4*)(SH + (size_t)cid1 * 4096 + off);
            cd_next = cumdecay[(size_t)cid1 * 64 + 63];
        }
        *(f32x4*)(SH + base) = H;
        H.x = cd * H.x + s.x;
        H.y = cd * H.y + s.y;
        H.z = cd * H.z + s.z;
        H.w = cd * H.w + s.w;
        cid += NH;
    }
}

// ---------------- P3: y += exp(Lc_t) * C_t @ H_in ----------------
__global__ __launch_bounds__(256) void inter_kernel(
    const short* __restrict__ xBCc, const float* __restrict__ Hin,
    const float* __restrict__ cumdecay, float* __restrict__ ybuf)
{
    int bid = blockIdx.x;
    int h = bid & 31, c = (bid >> 5) & 31, b = bid >> 10;
    int m0 = b * SEQ + c * Q;
    int tid = threadIdx.x;
    int wid = tid >> 6, lane = tid & 63, lm = lane & 15, lg = lane >> 4;

    __shared__ __attribute__((aligned(16))) short Cc[64 * LSTR];
    __shared__ __attribute__((aligned(16))) short HT[64 * LSTR];
    __shared__ float eLc[64];

    if (tid < 64) eLc[tid] = cumdecay[(size_t)bid * 64 + tid];
    {
        int row = tid >> 2, c0 = (tid & 3) * 16;
        const short* pC = xBCc + (size_t)(m0 + row) * CONV_DIM + DIN + DSTATE;
#pragma unroll
        for (int u = 0; u < 2; ++u) {
            short8 vc = *(const short8*)(pC + c0 + 8 * u);
            *(short8*)&Cc[row * LSTR + c0 + 8 * u] = vc;
        }
        const float* pH = Hin + (size_t)bid * 4096 + row * 64;
#pragma unroll
        for (int u = 0; u < 4; ++u) {
            f32x4 vh = *(const f32x4*)(pH + c0 + 4 * u);
            HT[(c0 + 4 * u + 0) * LSTR + row] = f2bf(vh.x);
            HT[(c0 + 4 * u + 1) * LSTR + row] = f2bf(vh.y);
            HT[(c0 + 4 * u + 2) * LSTR + row] = f2bf(vh.z);
            HT[(c0 + 4 * u + 3) * LSTR + row] = f2bf(vh.w);
        }
    }
    __syncthreads();

    bf16x8 af[2];
#pragma unroll
    for (int kk = 0; kk < 2; ++kk)
        af[kk] = ld_frag(&Cc[(wid * 16 + lm) * LSTR + kk * 32 + lg * 8]);
#pragma unroll
    for (int j = 0; j < 4; ++j) {
        f32x4 acc = {0.f, 0.f, 0.f, 0.f};
#pragma unroll
        for (int kk = 0; kk < 2; ++kk) {
            bf16x8 bh_ = ld_frag(&HT[(j * 16 + lm) * LSTR + kk * 32 + lg * 8]);
            acc = __builtin_amdgcn_mfma_f32_16x16x32_bf16(af[kk], bh_, acc, 0, 0, 0);
        }
        int p = j * 16 + lm;
#pragma unroll
        for (int r = 0; r < 4; ++r) {
            int t = wid * 16 + lg * 4 + r;
            size_t ya = (size_t)(m0 + t) * DIN + h * HEADDIM + p;
            ybuf[ya] += eLc[t] * acc[r];
        }
    }
}

// ---------------- ybf = bf16(rmsnorm((y + D*x) * silu(z), norm_w)) ----------
// G13: thread owns 8 contiguous elements -> short8/f32x4 loads, short8 store.
__global__ __launch_bounds__(256) void norm1_kernel(
    const short* __restrict__ zx, const short* __restrict__ xBCc,
    const float* __restrict__ Dp, const float* __restrict__ y,
    short* __restrict__ ybf, const float* __restrict__ w)
{
    int m = blockIdx.x;
    int t = threadIdx.x;
    int i0 = t * 8;
    const short8 zv = *(const short8*)(zx + (size_t)m * DPROJ + i0);
    const short8 xv = *(const short8*)(xBCc + (size_t)m * CONV_DIM + i0);
    const float* yr = y + (size_t)m * DIN + i0;
    f32x4 y0 = *(const f32x4*)(yr);
    f32x4 y1 = *(const f32x4*)(yr + 4);
    float Dv = Dp[i0 >> 6];           // 8 elems span one head (HEADDIM=64)

    float vals[8];
    float ss = 0.f;
#pragma unroll
    for (int j = 0; j < 8; ++j) {
        float yj = (j < 4) ? y0[j] : y1[j - 4];
        float v = (yj + Dv * bf2f(xv[j])) * silu_f(bf2f(zv[j]));
        vals[j] = v;
        ss += v * v;
    }
#pragma unroll
    for (int o = 32; o >= 1; o >>= 1) ss += __shfl_xor(ss, o);
    __shared__ float wsum[4];
    if ((t & 63) == 0) wsum[t >> 6] = ss;
    __syncthreads();
    float tot = wsum[0] + wsum[1] + wsum[2] + wsum[3];
    float scale = rsqrtf(tot / (float)DIN + EPS);

    f32x4 w0 = *(const f32x4*)(w + i0);
    f32x4 w1 = *(const f32x4*)(w + i0 + 4);
    short8 ov;
#pragma unroll
    for (int j = 0; j < 8; ++j) {
        float wj = (j < 4) ? w0[j] : w1[j - 4];
        ov[j] = f2bf(vals[j] * scale * wj);
    }
    *(short8*)(ybf + (size_t)m * DIN + i0) = ov;
}

// ---------------- hnbf = bf16(rmsnorm(h, rms_w)) ----------------
__global__ __launch_bounds__(256) void norm2_kernel(
    const float* __restrict__ hb, short* __restrict__ hnbf, const float* __restrict__ w)
{
    int m = blockIdx.x;
    int t = threadIdx.x;
    int i0 = t * 4;
    f32x4 hv = *(const f32x4*)(hb + (size_t)m * DMODEL + i0);
    float ss = hv.x * hv.x + hv.y * hv.y + hv.z * hv.z + hv.w * hv.w;
#pragma unroll
    for (int o = 32; o >= 1; o >>= 1) ss += __shfl_xor(ss, o);
    __shared__ float wsum[4];
    if ((t & 63) == 0) wsum[t >> 6] = ss;
    __syncthreads();
    float tot = wsum[0] + wsum[1] + wsum[2] + wsum[3];
    float scale = rsqrtf(tot / (float)DMODEL + EPS);
    f32x4 wv = *(const f32x4*)(w + i0);
    short4 ov;
    ov.x = f2bf(hv.x * scale * wv.x);
    ov.y = f2bf(hv.y * scale * wv.y);
    ov.z = f2bf(hv.z * scale * wv.z);
    ov.w = f2bf(hv.w * scale * wv.w);
    *(short4*)(hnbf + (size_t)m * DMODEL + i0) = ov;
}

extern "C" void kernel_launch(void* const* d_in, const int* in_sizes, int n_in,
                              void* d_out, int out_size, void* d_ws, size_t ws_size,
                              hipStream_t stream) {
    const float* x       = (const float*)d_in[0];
    const float* W_in    = (const float*)d_in[1];
    const float* conv_w  = (const float*)d_in[2];
    const float* conv_b  = (const float*)d_in[3];
    const float* dt_bias = (const float*)d_in[4];
    const float* A_log   = (const float*)d_in[5];
    const float* D_param = (const float*)d_in[6];
    const float* norm_w  = (const float*)d_in[7];
    const float* W_out   = (const float*)d_in[8];
    const float* rms_w   = (const float*)d_in[9];
    const float* mlp_w1  = (const float*)d_in[10];
    const float* mlp_b1  = (const float*)d_in[11];
    const float* mlp_w2  = (const float*)d_in[12];
    const float* mlp_b2  = (const float*)d_in[13];
    float* out = (float*)d_out;

    float* ws       = (float*)d_ws;
    float* zxf      = ws;                                  // holds bf16 zx
    float* xBCf     = zxf + (size_t)TOKENS * DPROJ;        // holds bf16 xBCc
    float* dtb      = xBCf + (size_t)TOKENS * CONV_DIM;
    float* ldab     = dtb + (size_t)TOKENS * NH;
    float* cumdecay = ldab + (size_t)TOKENS * NH;
    float* ybuf     = cumdecay + (size_t)TOKENS * NH;
    float* SH       = ybuf + (size_t)TOKENS * DIN;
    float* bfarea   = SH + (size_t)NCH * 4096;

    short* zxb   = (short*)zxf;
    short* xBCb  = (short*)xBCf;
    short* xbf   = (short*)ybuf;
    short* midbf = (short*)ybuf;
    float* hbuf  = SH;
    short* hnbf  = (short*)(SH + (size_t)TOKENS * DMODEL);

    short* ybf   = (short*)bfarea;
    short* WinT  = ybf + (size_t)TOKENS * DIN;
    short* WoutT = WinT + (size_t)NPAD_IN * DMODEL;
    short* w1T   = WoutT + (size_t)DMODEL * DIN;
    short* w2T   = w1T + (size_t)MLP_INNER * DMODEL;

    dim3 blk(256);

    // 0. conversions / weight transposes
    cvt_kernel<<<dim3(TOKENS * DMODEL / 4 / 256), blk, 0, stream>>>(x, xbf, TOKENS * DMODEL / 4);
    transpose_kernel<<<dim3(NPAD_IN / 32, DMODEL / 32), blk, 0, stream>>>(W_in, WinT, DMODEL, DPROJ);
    transpose_kernel<<<dim3(DMODEL / 32, DIN / 32), blk, 0, stream>>>(W_out, WoutT, DIN, DMODEL);
    transpose_kernel<<<dim3(MLP_INNER / 32, DMODEL / 32), blk, 0, stream>>>(mlp_w1, w1T, DMODEL, MLP_INNER);
    transpose_kernel<<<dim3(DMODEL / 32, MLP_INNER / 32), blk, 0, stream>>>(mlp_w2, w2T, MLP_INNER, DMODEL);

    // 1. zx = bf16(x @ W_in)  (64x128 tiles: 34 x 64 = 2176 blocks, 2 blk/CU)
    gemm64_kernel<4><<<dim3(NPAD_IN / 128, TOKENS / 64), blk, 0, stream>>>(
        xbf, WinT, zxb, nullptr, nullptr, TOKENS, DPROJ, DMODEL);
    // 2. conv + bias + silu (bf16 in/out, token-blocked)
    conv_kernel<<<dim3(TOKENS / CTOK, (CONV_DIM / 4 + 255) / 256), blk, 0, stream>>>(
        zxb, conv_w, conv_b, xBCb);
    // 3. dt / ldA
    dt_kernel<<<dim3(TOKENS * NH / 256), blk, 0, stream>>>(zxb, dt_bias, A_log, dtb, ldab);
    // 4. SSD
    chunk_kernel<<<dim3(NCH), blk, 0, stream>>>(xBCb, dtb, ldab, ybuf, SH, cumdecay);
    state_kernel<<<dim3(BATCH * NH * 4), blk, 0, stream>>>(SH, cumdecay);
    inter_kernel<<<dim3(NCH), blk, 0, stream>>>(xBCb, SH, cumdecay, ybuf);
    // 5. ybf = bf16(rmsnorm((y + D*x) * silu(z)))
    norm1_kernel<<<dim3(TOKENS), blk, 0, stream>>>(zxb, xBCb, D_param, ybuf, ybf, norm_w);
    // 6. h = x + ybf @ W_out  (64x128 tiles: 8 x 64 = 512 blocks, 2 blk/CU)
    gemm64_kernel<3><<<dim3(DMODEL / 128, TOKENS / 64), blk, 0, stream>>>(
        ybf, WoutT, hbuf, nullptr, x, TOKENS, DMODEL, DIN);
    // 7. hnbf = bf16(rmsnorm(h))
    norm2_kernel<<<dim3(TOKENS), blk, 0, stream>>>(hbuf, hnbf, rms_w);
    // 8. midbf = bf16(silu(hnbf @ mlp_w1 + b1))  (64x128 tiles: 32 x 64 = 2048 blocks)
    gemm64_kernel<1><<<dim3(MLP_INNER / 128, TOKENS / 64), blk, 0, stream>>>(
        hnbf, w1T, midbf, mlp_b1, nullptr, TOKENS, MLP_INNER, DMODEL);
    // 9. out = h + midbf @ mlp_w2 + b2  (64x128 tiles: 512 blocks, 2 blk/CU)
    gemm64_kernel<2><<<dim3(DMODEL / 128, TOKENS / 64), blk, 0, stream>>>(
        midbf, w2T, out, mlp_b2, hbuf, TOKENS, DMODEL, MLP_INNER);
}

// Round 8
// 394.258 us; speedup vs baseline: 1.0469x; 1.0371x over previous
//
#include <hip/hip_runtime.h>
#include <hip/hip_bf16.h>
#include <cstdint>
#include <cstddef>

#define BATCH 2
#define SEQ 2048
#define DMODEL 1024
#define DIN 2048
#define NH 32
#define HEADDIM 64
#define DSTATE 64
#define DCONV 4
#define CONV_DIM (DIN + 2 * DSTATE)          // 2176
#define DPROJ (2 * DIN + 2 * DSTATE + NH)    // 4256
#define MLP_INNER 4096
#define TOKENS (BATCH * SEQ)                 // 4096
#define EPS 1e-5f
#define Q 64
#define NCHUNK (SEQ / Q)                     // 32
#define NCH (BATCH * NCHUNK * NH)            // 2048 chunk-heads
#define LSTR 72                               // 144B rows (16B-aligned)
#define NPAD_IN 4352                          // DPROJ padded to 34*128

typedef __attribute__((ext_vector_type(8))) short short8;
typedef __attribute__((ext_vector_type(8))) __bf16 bf16x8;
typedef __attribute__((ext_vector_type(4))) float f32x4;

__device__ inline short f2bf(float f) {
    unsigned u = __builtin_bit_cast(unsigned, f);
    u = (u + 0x7FFFu + ((u >> 16) & 1u)) >> 16;
    return (short)u;
}
__device__ inline float bf2f(short s) {
    unsigned u = ((unsigned)(unsigned short)s) << 16;
    return __builtin_bit_cast(float, u);
}
__device__ inline float silu_f(float x) { return x / (1.f + __expf(-x)); }

__device__ inline bf16x8 ld_frag(const short* p) {
    short8 s = *(const short8*)p;
    return __builtin_bit_cast(bf16x8, s);
}

__device__ inline void glds16(const short* g, short* l) {
    __builtin_amdgcn_global_load_lds(
        (const __attribute__((address_space(1))) void*)g,
        (__attribute__((address_space(3))) void*)l, 16, 0, 0);
}

// ---------------- 128x128-tile bf16 GEMM, KT=64 (K=1024 GEMMs) -------------
// m97 structure, KT=64: 64KB LDS -> 2 blk/CU. vs the 64x128 tile (R6, 55us):
// half the block-iterations (GEMM1: 68 vs 136 per CU) and 2x arithmetic
// intensity, same 0-conflict 8-slot XOR swizzle, same 2-deep co-residency.
// Latency-bound regime (R6: MFMA 25%/VALU 35%/HBM 32%, ~970cyc per barrier-
// quantized block-iter) -> fewer, fatter iterations amortize the per-iter
// vmcnt(0) drain. MODE 1: bf16 C=silu(AB+bias); MODE 4: bf16 C=AB.
template <int MODE, int KT>
__global__ __launch_bounds__(256, (KT == 32) ? 4 : 2) void gemm_bf16_kernel(
    const short* __restrict__ A, const short* __restrict__ BT,
    void* __restrict__ Cout, const float* __restrict__ bias,
    const float* __restrict__ res, int M, int N, int K)
{
    const int tid  = threadIdx.x;
    const int wid  = tid >> 6;
    const int lane = tid & 63;
    const int lm   = lane & 15;
    const int lg   = lane >> 4;

    const int nb  = gridDim.x * gridDim.y;
    const int bid = blockIdx.y * gridDim.x + blockIdx.x;
    const int per = nb >> 3;
    const int nid = (bid & 7) * per + (bid >> 3);
    const int m0  = (nid / gridDim.x) * 128;
    const int n0  = (nid % gridDim.x) * 128;

    __shared__ __attribute__((aligned(16))) short Al0[128 * KT];
    __shared__ __attribute__((aligned(16))) short Al1[128 * KT];
    __shared__ __attribute__((aligned(16))) short Bl0[128 * KT];
    __shared__ __attribute__((aligned(16))) short Bl1[128 * KT];

    f32x4 acc[4][4];
#pragma unroll
    for (int i = 0; i < 4; ++i)
#pragma unroll
        for (int j = 0; j < 4; ++j) acc[i][j] = {0.f, 0.f, 0.f, 0.f};

    const int wm = (wid >> 1) * 64;
    const int wn = (wid & 1) * 64;

    constexpr int lpr = KT / 8;      // 16B blocks per row
    constexpr int rpi = 64 / lpr;    // rows per glds16 instr
    constexpr int nin = 32 / rpi;    // glds16 instrs per matrix per wave
    const int srow = lane / lpr;
    const int scb  = (lane % lpr) ^ (srow & (lpr - 1));   // swizzled source block
    const int scol = scb * 8;
    const short* Ag = A  + (size_t)(m0 + wid * 32 + srow) * K + scol;
    const short* Bg = BT + (size_t)(n0 + wid * 32 + srow) * K + scol;
    const int woff = wid * 32 * KT;

    const int niter = K / KT;
    {
#pragma unroll
        for (int j = 0; j < nin; ++j) {
            glds16(Ag + (size_t)j * rpi * K, Al0 + woff + j * 512);
            glds16(Bg + (size_t)j * rpi * K, Bl0 + woff + j * 512);
        }
    }

    for (int i = 0; i < niter; ++i) {
        __syncthreads();
        const short* Ac = (i & 1) ? Al1 : Al0;
        const short* Bc = (i & 1) ? Bl1 : Bl0;
        if (i + 1 < niter) {
            int kt = (i + 1) * KT;
            short* al = ((i & 1) ? Al0 : Al1) + woff;
            short* bl = ((i & 1) ? Bl0 : Bl1) + woff;
#pragma unroll
            for (int j = 0; j < nin; ++j) {
                glds16(Ag + kt + (size_t)j * rpi * K, al + j * 512);
                glds16(Bg + kt + (size_t)j * rpi * K, bl + j * 512);
            }
        }

#pragma unroll
        for (int sub = 0; sub < KT / 32; ++sub) {
            const int cb = sub * 4 + lg;
            bf16x8 af[4], bf[4];
#pragma unroll
            for (int ii = 0; ii < 4; ++ii) {
                int ar = wm + ii * 16 + lm;
                af[ii] = ld_frag(&Ac[ar * KT + ((cb ^ (ar & (lpr - 1))) * 8)]);
            }
#pragma unroll
            for (int j = 0; j < 4; ++j) {
                int br = wn + j * 16 + lm;
                bf[j] = ld_frag(&Bc[br * KT + ((cb ^ (br & (lpr - 1))) * 8)]);
            }
#pragma unroll
            for (int ii = 0; ii < 4; ++ii)
#pragma unroll
                for (int j = 0; j < 4; ++j)
                    acc[ii][j] = __builtin_amdgcn_mfma_f32_16x16x32_bf16(af[ii], bf[j], acc[ii][j], 0, 0, 0);
        }
    }

#pragma unroll
    for (int i = 0; i < 4; ++i) {
#pragma unroll
        for (int j = 0; j < 4; ++j) {
            int col = n0 + wn + j * 16 + lm;
            if (col >= N) continue;
            float bv = (MODE == 1 || MODE == 2) ? bias[col] : 0.f;
#pragma unroll
            for (int r = 0; r < 4; ++r) {
                int row = m0 + wm + i * 16 + lg * 4 + r;
                float v = acc[i][j][r];
                if (MODE == 1) {
                    ((short*)Cout)[(size_t)row * N + col] = f2bf(silu_f(v + bv));
                } else if (MODE == 4) {
                    ((short*)Cout)[(size_t)row * N + col] = f2bf(v);
                } else {
                    if (MODE == 2) v = v + bv + res[(size_t)row * N + col];
                    if (MODE == 3) v = v + res[(size_t)row * N + col];
                    ((float*)Cout)[(size_t)row * N + col] = v;
                }
            }
        }
    }
}

// ---------------- 64x128-tile bf16 GEMM, KT=64 (N=1024 GEMMs) --------------
// 512 blocks -> 2 blk/CU (48KB LDS). Kept for W_out / MLP-down where a 128^2
// tile would give only 256 blocks = 1 blk/CU (R3 lesson).
// MODE 2: f32 C=AB+bias+res ; MODE 3: f32 C=AB+res.
template <int MODE>
__global__ __launch_bounds__(256, 2) void gemm64_kernel(
    const short* __restrict__ A, const short* __restrict__ BT,
    void* __restrict__ Cout, const float* __restrict__ bias,
    const float* __restrict__ res, int M, int N, int K)
{
    constexpr int KT = 64;
    const int tid  = threadIdx.x;
    const int wid  = tid >> 6;
    const int lane = tid & 63;
    const int lm   = lane & 15;
    const int lg   = lane >> 4;
    const int wn   = wid * 32;

    const int nb  = gridDim.x * gridDim.y;
    const int bid = blockIdx.y * gridDim.x + blockIdx.x;
    const int per = nb >> 3;
    const int nid = (bid & 7) * per + (bid >> 3);
    const int m0  = (nid / gridDim.x) * 64;
    const int n0  = (nid % gridDim.x) * 128;

    __shared__ __attribute__((aligned(16))) short Al0[64 * KT];
    __shared__ __attribute__((aligned(16))) short Al1[64 * KT];
    __shared__ __attribute__((aligned(16))) short Bl0[128 * KT];
    __shared__ __attribute__((aligned(16))) short Bl1[128 * KT];

    f32x4 acc[4][2];
#pragma unroll
    for (int i = 0; i < 4; ++i)
#pragma unroll
        for (int j = 0; j < 2; ++j) acc[i][j] = {0.f, 0.f, 0.f, 0.f};

    const int srow = lane >> 3;
    const int scb  = (lane & 7) ^ (srow & 7);
    const int scol = scb * 8;
    const short* Bg = BT + (size_t)(n0 + wid * 32 + srow) * K + scol;
    const short* Ag = A  + (size_t)(m0 + (wid & 1) * 32 + srow) * K + scol;
    const int woffB = wid * 32 * KT;
    const int woffA = (wid & 1) * 32 * KT;
    const bool doA = (wid < 2);

    const int niter = K / KT;
    {
#pragma unroll
        for (int j = 0; j < 4; ++j) {
            if (doA) glds16(Ag + (size_t)j * 8 * K, Al0 + woffA + j * 512);
            glds16(Bg + (size_t)j * 8 * K, Bl0 + woffB + j * 512);
        }
    }

    for (int i = 0; i < niter; ++i) {
        __syncthreads();
        const short* Ac = (i & 1) ? Al1 : Al0;
        const short* Bc = (i & 1) ? Bl1 : Bl0;
        if (i + 1 < niter) {
            int kt = (i + 1) * KT;
            short* al = ((i & 1) ? Al0 : Al1) + woffA;
            short* bl = ((i & 1) ? Bl0 : Bl1) + woffB;
#pragma unroll
            for (int j = 0; j < 4; ++j) {
                if (doA) glds16(Ag + kt + (size_t)j * 8 * K, al + j * 512);
                glds16(Bg + kt + (size_t)j * 8 * K, bl + j * 512);
            }
        }

#pragma unroll
        for (int sub = 0; sub < 2; ++sub) {
            const int cb = sub * 4 + lg;
            bf16x8 af[4], bf[2];
#pragma unroll
            for (int ii = 0; ii < 4; ++ii) {
                int ar = ii * 16 + lm;
                af[ii] = ld_frag(&Ac[ar * KT + ((cb ^ (ar & 7)) * 8)]);
            }
#pragma unroll
            for (int j = 0; j < 2; ++j) {
                int br = wn + j * 16 + lm;
                bf[j] = ld_frag(&Bc[br * KT + ((cb ^ (br & 7)) * 8)]);
            }
#pragma unroll
            for (int ii = 0; ii < 4; ++ii)
#pragma unroll
                for (int j = 0; j < 2; ++j)
                    acc[ii][j] = __builtin_amdgcn_mfma_f32_16x16x32_bf16(af[ii], bf[j], acc[ii][j], 0, 0, 0);
        }
    }

#pragma unroll
    for (int j = 0; j < 2; ++j) {
        int col = n0 + wn + j * 16 + lm;
        float bv = (MODE == 2) ? bias[col] : 0.f;
#pragma unroll
        for (int i = 0; i < 4; ++i) {
#pragma unroll
            for (int r = 0; r < 4; ++r) {
                int row = m0 + i * 16 + lg * 4 + r;
                float v = acc[i][j][r] + bv + res[(size_t)row * N + col];
                ((float*)Cout)[(size_t)row * N + col] = v;
            }
        }
    }
}

// ---------------- f32 -> bf16 convert ----------------
__global__ __launch_bounds__(256) void cvt_kernel(
    const float* __restrict__ src, short* __restrict__ dst, int n4)
{
    int i = (blockIdx.x * 256 + threadIdx.x);
    if (i >= n4) return;
    f32x4 v = *(const f32x4*)(src + (size_t)i * 4);
    short4 o;
    o.x = f2bf(v.x); o.y = f2bf(v.y); o.z = f2bf(v.z); o.w = f2bf(v.w);
    *(short4*)(dst + (size_t)i * 4) = o;
}

// ---------------- W [K][N] f32 -> WT [Npad][K] bf16 ----------------
__global__ __launch_bounds__(256) void transpose_kernel(
    const float* __restrict__ src, short* __restrict__ dst, int K, int N)
{
    __shared__ float t[32][33];
    int bx = blockIdx.x, by = blockIdx.y;
    int col = threadIdx.x & 31, row8 = threadIdx.x >> 5;
    int gn = bx * 32 + col;
#pragma unroll
    for (int r = 0; r < 4; ++r) {
        int gk = by * 32 + row8 + r * 8;
        t[row8 + r * 8][col] = (gn < N) ? src[(size_t)gk * N + gn] : 0.f;
    }
    __syncthreads();
#pragma unroll
    for (int r = 0; r < 4; ++r) {
        int n = bx * 32 + row8 + r * 8;
        dst[(size_t)n * K + by * 32 + col] = f2bf(t[col][row8 + r * 8]);
    }
}

// ---------------- depthwise causal conv (k=4) + bias + silu, bf16 in/out ----
#define CTOK 8
__global__ __launch_bounds__(256) void conv_kernel(
    const short* __restrict__ zx, const float* __restrict__ cw,
    const float* __restrict__ cb, short* __restrict__ xBCc)
{
    int c4 = blockIdx.y * 256 + threadIdx.x;
    if (c4 >= CONV_DIM / 4) return;
    int c  = c4 * 4;
    int m0 = blockIdx.x * CTOK;
    int l0 = m0 & (SEQ - 1);

    const short* base = zx + (size_t)m0 * DPROJ + DIN + c;
    f32x4 win[CTOK + 3];
#pragma unroll
    for (int j = 0; j < CTOK + 3; ++j) {
        int off = j - 3;
        if (l0 + off >= 0) {
            short4 sv = *(const short4*)(base + (ptrdiff_t)off * DPROJ);
            win[j] = {bf2f(sv.x), bf2f(sv.y), bf2f(sv.z), bf2f(sv.w)};
        } else {
            win[j] = {0.f, 0.f, 0.f, 0.f};
        }
    }
    f32x4 w0 = *(const f32x4*)(cw + (c + 0) * DCONV);
    f32x4 w1 = *(const f32x4*)(cw + (c + 1) * DCONV);
    f32x4 w2 = *(const f32x4*)(cw + (c + 2) * DCONV);
    f32x4 w3 = *(const f32x4*)(cw + (c + 3) * DCONV);
    f32x4 bb = *(const f32x4*)(cb + c);

    short* outp = xBCc + (size_t)m0 * CONV_DIM + c;
#pragma unroll
    for (int t = 0; t < CTOK; ++t) {
        f32x4 a = {bb.x, bb.y, bb.z, bb.w};
#pragma unroll
        for (int j = 0; j < DCONV; ++j) {
            f32x4 v = win[t + j];
            a.x += v.x * w0[j];
            a.y += v.y * w1[j];
            a.z += v.z * w2[j];
            a.w += v.w * w3[j];
        }
        short4 o;
        o.x = f2bf(silu_f(a.x)); o.y = f2bf(silu_f(a.y));
        o.z = f2bf(silu_f(a.z)); o.w = f2bf(silu_f(a.w));
        *(short4*)(outp + (size_t)t * CONV_DIM) = o;
    }
}

// ---------------- dt = softplus(dt_raw + bias); ldA = A * dt ----------------
__global__ __launch_bounds__(256) void dt_kernel(
    const short* __restrict__ zx, const float* __restrict__ dt_bias,
    const float* __restrict__ A_log, float* __restrict__ dtb, float* __restrict__ ldab)
{
    int idx = blockIdx.x * 256 + threadIdx.x;
    if (idx >= TOKENS * NH) return;
    int hh = idx & (NH - 1);
    int m  = idx >> 5;
    float v  = bf2f(zx[(size_t)m * DPROJ + DIN + CONV_DIM + hh]) + dt_bias[hh];
    float dt = (v > 20.f) ? v : log1pf(__expf(v));
    dtb[idx]  = dt;
    ldab[idx] = -__expf(A_log[hh]) * dt;
}

// ---------------- P1: intra-chunk SSD (bf16 xBCc) ----------------
__global__ __launch_bounds__(256) void chunk_kernel(
    const short* __restrict__ xBCc, const float* __restrict__ dtb,
    const float* __restrict__ ldab, float* __restrict__ ybuf,
    float* __restrict__ Sbuf, float* __restrict__ cumdecay)
{
    int bid = blockIdx.x;
    int h = bid & 31, c = (bid >> 5) & 31, b = bid >> 10;
    int m0 = b * SEQ + c * Q;
    int tid = threadIdx.x;
    int wid = tid >> 6, lane = tid & 63, lm = lane & 15, lg = lane >> 4;

    __shared__ __attribute__((aligned(16))) short Cc[64 * LSTR];
    __shared__ __attribute__((aligned(16))) short Bb[64 * LSTR];
    __shared__ __attribute__((aligned(16))) short BwT[64 * LSTR];
    __shared__ __attribute__((aligned(16))) short Xt[64 * LSTR];
    __shared__ __attribute__((aligned(16))) short Mm[64 * LSTR];
    __shared__ float Lc[64], dtv[64];

    if (tid < 64) {
        int s = tid;
        size_t ix = (size_t)(m0 + s) * NH + h;
        float ld = ldab[ix];
        float dt = dtb[ix];
        float v = ld;
#pragma unroll
        for (int off = 1; off < 64; off <<= 1) {
            float o = __shfl_up(v, off);
            if (s >= off) v += o;
        }
        Lc[s] = v;
        dtv[s] = dt;
        cumdecay[(size_t)bid * 64 + s] = __expf(v);
    }
    {
        int row = tid >> 2, c0 = (tid & 3) * 16;
        const short* pB = xBCc + (size_t)(m0 + row) * CONV_DIM + DIN;
#pragma unroll
        for (int u = 0; u < 2; ++u) {
            short8 vb = *(const short8*)(pB + c0 + 8 * u);
            short8 vc = *(const short8*)(pB + DSTATE + c0 + 8 * u);
            *(short8*)&Bb[row * LSTR + c0 + 8 * u] = vb;
            *(short8*)&Cc[row * LSTR + c0 + 8 * u] = vc;
        }
    }
    __syncthreads();
    {
        int s = tid >> 2, c0 = (tid & 3) * 16;
        float w = dtv[s];
        float w2 = __expf(Lc[63] - Lc[s]);
        const short* pX = xBCc + (size_t)(m0 + s) * CONV_DIM + h * HEADDIM;
#pragma unroll
        for (int u = 0; u < 4; ++u) {
            short4 v = *(const short4*)(pX + c0 + 4 * u);
            Xt[(c0 + 4 * u + 0) * LSTR + s] = f2bf(bf2f(v.x) * w);
            Xt[(c0 + 4 * u + 1) * LSTR + s] = f2bf(bf2f(v.y) * w);
            Xt[(c0 + 4 * u + 2) * LSTR + s] = f2bf(bf2f(v.z) * w);
            Xt[(c0 + 4 * u + 3) * LSTR + s] = f2bf(bf2f(v.w) * w);
            short4 sb = *(short4*)&Bb[s * LSTR + c0 + 4 * u];
            BwT[(c0 + 4 * u + 0) * LSTR + s] = f2bf(bf2f(sb.x) * w2);
            BwT[(c0 + 4 * u + 1) * LSTR + s] = f2bf(bf2f(sb.y) * w2);
            BwT[(c0 + 4 * u + 2) * LSTR + s] = f2bf(bf2f(sb.z) * w2);
            BwT[(c0 + 4 * u + 3) * LSTR + s] = f2bf(bf2f(sb.w) * w2);
        }
    }
    __syncthreads();

    {
        bf16x8 af[2];
#pragma unroll
        for (int kk = 0; kk < 2; ++kk)
            af[kk] = ld_frag(&Cc[(wid * 16 + lm) * LSTR + kk * 32 + lg * 8]);
#pragma unroll
        for (int j = 0; j < 4; ++j) {
            f32x4 acc = {0.f, 0.f, 0.f, 0.f};
#pragma unroll
            for (int kk = 0; kk < 2; ++kk) {
                bf16x8 bf = ld_frag(&Bb[(j * 16 + lm) * LSTR + kk * 32 + lg * 8]);
                acc = __builtin_amdgcn_mfma_f32_16x16x32_bf16(af[kk], bf, acc, 0, 0, 0);
            }
            int s = j * 16 + lm;
            float Ls = Lc[s];
#pragma unroll
            for (int r = 0; r < 4; ++r) {
                int t = wid * 16 + lg * 4 + r;
                float val = (s <= t) ? acc[r] * __expf(Lc[t] - Ls) : 0.f;
                Mm[t * LSTR + s] = f2bf(val);
            }
        }
    }
    __syncthreads();

    {
        bf16x8 am[2], aw[2];
#pragma unroll
        for (int kk = 0; kk < 2; ++kk) {
            am[kk] = ld_frag(&Mm[(wid * 16 + lm) * LSTR + kk * 32 + lg * 8]);
            aw[kk] = ld_frag(&BwT[(wid * 16 + lm) * LSTR + kk * 32 + lg * 8]);
        }
#pragma unroll
        for (int j = 0; j < 4; ++j) {
            f32x4 a1 = {0.f, 0.f, 0.f, 0.f};
            f32x4 a2 = {0.f, 0.f, 0.f, 0.f};
#pragma unroll
            for (int kk = 0; kk < 2; ++kk) {
                bf16x8 bx = ld_frag(&Xt[(j * 16 + lm) * LSTR + kk * 32 + lg * 8]);
                a1 = __builtin_amdgcn_mfma_f32_16x16x32_bf16(am[kk], bx, a1, 0, 0, 0);
                a2 = __builtin_amdgcn_mfma_f32_16x16x32_bf16(aw[kk], bx, a2, 0, 0, 0);
            }
            int p = j * 16 + lm;
#pragma unroll
            for (int r = 0; r < 4; ++r) {
                int t = wid * 16 + lg * 4 + r;
                ybuf[(size_t)(m0 + t) * DIN + h * HEADDIM + p] = a1[r];
                Sbuf[(size_t)bid * 4096 + t * 64 + p] = a2[r];
            }
        }
    }
}

// ---------------- P2: inter-chunk state recurrence (256 blocks + prefetch) --
__global__ __launch_bounds__(256) void state_kernel(
    float* __restrict__ SH, const float* __restrict__ cumdecay)
{
    int bh = blockIdx.x >> 2, st = blockIdx.x & 3;
    int b = bh >> 5, h = bh & 31;
    size_t off = (size_t)st * 1024 + (size_t)threadIdx.x * 4;

    f32x4 H = {0.f, 0.f, 0.f, 0.f};
    int cid = b * NCHUNK * NH + h;
    f32x4 s_next = *(const f32x4*)(SH + (size_t)cid * 4096 + off);
    float cd_next = cumdecay[(size_t)cid * 64 + 63];

    for (int c = 0; c < NCHUNK; ++c) {
        f32x4 s = s_next;
        float cd = cd_next;
        size_t base = (size_t)cid * 4096 + off;
        if (c + 1 < NCHUNK) {
            int cid1 = cid + NH;
            s_next = *(const f32x4*)(SH + (size_t)cid1 * 4096 + off);
            cd_next = cumdecay[(size_t)cid1 * 64 + 63];
        }
        *(f32x4*)(SH + base) = H;
        H.x = cd * H.x + s.x;
        H.y = cd * H.y + s.y;
        H.z = cd * H.z + s.z;
        H.w = cd * H.w + s.w;
        cid += NH;
    }
}

// ---------------- P3: y += exp(Lc_t) * C_t @ H_in ----------------
__global__ __launch_bounds__(256) void inter_kernel(
    const short* __restrict__ xBCc, const float* __restrict__ Hin,
    const float* __restrict__ cumdecay, float* __restrict__ ybuf)
{
    int bid = blockIdx.x;
    int h = bid & 31, c = (bid >> 5) & 31, b = bid >> 10;
    int m0 = b * SEQ + c * Q;
    int tid = threadIdx.x;
    int wid = tid >> 6, lane = tid & 63, lm = lane & 15, lg = lane >> 4;

    __shared__ __attribute__((aligned(16))) short Cc[64 * LSTR];
    __shared__ __attribute__((aligned(16))) short HT[64 * LSTR];
    __shared__ float eLc[64];

    if (tid < 64) eLc[tid] = cumdecay[(size_t)bid * 64 + tid];
    {
        int row = tid >> 2, c0 = (tid & 3) * 16;
        const short* pC = xBCc + (size_t)(m0 + row) * CONV_DIM + DIN + DSTATE;
#pragma unroll
        for (int u = 0; u < 2; ++u) {
            short8 vc = *(const short8*)(pC + c0 + 8 * u);
            *(short8*)&Cc[row * LSTR + c0 + 8 * u] = vc;
        }
        const float* pH = Hin + (size_t)bid * 4096 + row * 64;
#pragma unroll
        for (int u = 0; u < 4; ++u) {
            f32x4 vh = *(const f32x4*)(pH + c0 + 4 * u);
            HT[(c0 + 4 * u + 0) * LSTR + row] = f2bf(vh.x);
            HT[(c0 + 4 * u + 1) * LSTR + row] = f2bf(vh.y);
            HT[(c0 + 4 * u + 2) * LSTR + row] = f2bf(vh.z);
            HT[(c0 + 4 * u + 3) * LSTR + row] = f2bf(vh.w);
        }
    }
    __syncthreads();

    bf16x8 af[2];
#pragma unroll
    for (int kk = 0; kk < 2; ++kk)
        af[kk] = ld_frag(&Cc[(wid * 16 + lm) * LSTR + kk * 32 + lg * 8]);
#pragma unroll
    for (int j = 0; j < 4; ++j) {
        f32x4 acc = {0.f, 0.f, 0.f, 0.f};
#pragma unroll
        for (int kk = 0; kk < 2; ++kk) {
            bf16x8 bh_ = ld_frag(&HT[(j * 16 + lm) * LSTR + kk * 32 + lg * 8]);
            acc = __builtin_amdgcn_mfma_f32_16x16x32_bf16(af[kk], bh_, acc, 0, 0, 0);
        }
        int p = j * 16 + lm;
#pragma unroll
        for (int r = 0; r < 4; ++r) {
            int t = wid * 16 + lg * 4 + r;
            size_t ya = (size_t)(m0 + t) * DIN + h * HEADDIM + p;
            ybuf[ya] += eLc[t] * acc[r];
        }
    }
}

// ---------------- ybf = bf16(rmsnorm((y + D*x) * silu(z), norm_w)) ----------
__global__ __launch_bounds__(256) void norm1_kernel(
    const short* __restrict__ zx, const short* __restrict__ xBCc,
    const float* __restrict__ Dp, const float* __restrict__ y,
    short* __restrict__ ybf, const float* __restrict__ w)
{
    int m = blockIdx.x;
    int t = threadIdx.x;
    int i0 = t * 8;
    const short8 zv = *(const short8*)(zx + (size_t)m * DPROJ + i0);
    const short8 xv = *(const short8*)(xBCc + (size_t)m * CONV_DIM + i0);
    const float* yr = y + (size_t)m * DIN + i0;
    f32x4 y0 = *(const f32x4*)(yr);
    f32x4 y1 = *(const f32x4*)(yr + 4);
    float Dv = Dp[i0 >> 6];           // 8 elems span one head (HEADDIM=64)

    float vals[8];
    float ss = 0.f;
#pragma unroll
    for (int j = 0; j < 8; ++j) {
        float yj = (j < 4) ? y0[j] : y1[j - 4];
        float v = (yj + Dv * bf2f(xv[j])) * silu_f(bf2f(zv[j]));
        vals[j] = v;
        ss += v * v;
    }
#pragma unroll
    for (int o = 32; o >= 1; o >>= 1) ss += __shfl_xor(ss, o);
    __shared__ float wsum[4];
    if ((t & 63) == 0) wsum[t >> 6] = ss;
    __syncthreads();
    float tot = wsum[0] + wsum[1] + wsum[2] + wsum[3];
    float scale = rsqrtf(tot / (float)DIN + EPS);

    f32x4 w0 = *(const f32x4*)(w + i0);
    f32x4 w1 = *(const f32x4*)(w + i0 + 4);
    short8 ov;
#pragma unroll
    for (int j = 0; j < 8; ++j) {
        float wj = (j < 4) ? w0[j] : w1[j - 4];
        ov[j] = f2bf(vals[j] * scale * wj);
    }
    *(short8*)(ybf + (size_t)m * DIN + i0) = ov;
}

// ---------------- hnbf = bf16(rmsnorm(h, rms_w)) ----------------
__global__ __launch_bounds__(256) void norm2_kernel(
    const float* __restrict__ hb, short* __restrict__ hnbf, const float* __restrict__ w)
{
    int m = blockIdx.x;
    int t = threadIdx.x;
    int i0 = t * 4;
    f32x4 hv = *(const f32x4*)(hb + (size_t)m * DMODEL + i0);
    float ss = hv.x * hv.x + hv.y * hv.y + hv.z * hv.z + hv.w * hv.w;
#pragma unroll
    for (int o = 32; o >= 1; o >>= 1) ss += __shfl_xor(ss, o);
    __shared__ float wsum[4];
    if ((t & 63) == 0) wsum[t >> 6] = ss;
    __syncthreads();
    float tot = wsum[0] + wsum[1] + wsum[2] + wsum[3];
    float scale = rsqrtf(tot / (float)DMODEL + EPS);
    f32x4 wv = *(const f32x4*)(w + i0);
    short4 ov;
    ov.x = f2bf(hv.x * scale * wv.x);
    ov.y = f2bf(hv.y * scale * wv.y);
    ov.z = f2bf(hv.z * scale * wv.z);
    ov.w = f2bf(hv.w * scale * wv.w);
    *(short4*)(hnbf + (size_t)m * DMODEL + i0) = ov;
}

extern "C" void kernel_launch(void* const* d_in, const int* in_sizes, int n_in,
                              void* d_out, int out_size, void* d_ws, size_t ws_size,
                              hipStream_t stream) {
    const float* x       = (const float*)d_in[0];
    const float* W_in    = (const float*)d_in[1];
    const float* conv_w  = (const float*)d_in[2];
    const float* conv_b  = (const float*)d_in[3];
    const float* dt_bias = (const float*)d_in[4];
    const float* A_log   = (const float*)d_in[5];
    const float* D_param = (const float*)d_in[6];
    const float* norm_w  = (const float*)d_in[7];
    const float* W_out   = (const float*)d_in[8];
    const float* rms_w   = (const float*)d_in[9];
    const float* mlp_w1  = (const float*)d_in[10];
    const float* mlp_b1  = (const float*)d_in[11];
    const float* mlp_w2  = (const float*)d_in[12];
    const float* mlp_b2  = (const float*)d_in[13];
    float* out = (float*)d_out;

    float* ws       = (float*)d_ws;
    float* zxf      = ws;                                  // holds bf16 zx
    float* xBCf     = zxf + (size_t)TOKENS * DPROJ;        // holds bf16 xBCc
    float* dtb      = xBCf + (size_t)TOKENS * CONV_DIM;
    float* ldab     = dtb + (size_t)TOKENS * NH;
    float* cumdecay = ldab + (size_t)TOKENS * NH;
    float* ybuf     = cumdecay + (size_t)TOKENS * NH;
    float* SH       = ybuf + (size_t)TOKENS * DIN;
    float* bfarea   = SH + (size_t)NCH * 4096;

    short* zxb   = (short*)zxf;
    short* xBCb  = (short*)xBCf;
    short* xbf   = (short*)ybuf;
    short* midbf = (short*)ybuf;
    float* hbuf  = SH;
    short* hnbf  = (short*)(SH + (size_t)TOKENS * DMODEL);

    short* ybf   = (short*)bfarea;
    short* WinT  = ybf + (size_t)TOKENS * DIN;
    short* WoutT = WinT + (size_t)NPAD_IN * DMODEL;
    short* w1T   = WoutT + (size_t)DMODEL * DIN;
    short* w2T   = w1T + (size_t)MLP_INNER * DMODEL;

    dim3 blk(256);

    // 0. conversions / weight transposes
    cvt_kernel<<<dim3(TOKENS * DMODEL / 4 / 256), blk, 0, stream>>>(x, xbf, TOKENS * DMODEL / 4);
    transpose_kernel<<<dim3(NPAD_IN / 32, DMODEL / 32), blk, 0, stream>>>(W_in, WinT, DMODEL, DPROJ);
    transpose_kernel<<<dim3(DMODEL / 32, DIN / 32), blk, 0, stream>>>(W_out, WoutT, DIN, DMODEL);
    transpose_kernel<<<dim3(MLP_INNER / 32, DMODEL / 32), blk, 0, stream>>>(mlp_w1, w1T, DMODEL, MLP_INNER);
    transpose_kernel<<<dim3(DMODEL / 32, MLP_INNER / 32), blk, 0, stream>>>(mlp_w2, w2T, MLP_INNER, DMODEL);

    // 1. zx = bf16(x @ W_in)  (128^2 KT=64: 34 x 32 = 1088 blocks, 2 blk/CU)
    gemm_bf16_kernel<4, 64><<<dim3(NPAD_IN / 128, TOKENS / 128), blk, 0, stream>>>(
        xbf, WinT, zxb, nullptr, nullptr, TOKENS, DPROJ, DMODEL);
    // 2. conv + bias + silu (bf16 in/out, token-blocked)
    conv_kernel<<<dim3(TOKENS / CTOK, (CONV_DIM / 4 + 255) / 256), blk, 0, stream>>>(
        zxb, conv_w, conv_b, xBCb);
    // 3. dt / ldA
    dt_kernel<<<dim3(TOKENS * NH / 256), blk, 0, stream>>>(zxb, dt_bias, A_log, dtb, ldab);
    // 4. SSD
    chunk_kernel<<<dim3(NCH), blk, 0, stream>>>(xBCb, dtb, ldab, ybuf, SH, cumdecay);
    state_kernel<<<dim3(BATCH * NH * 4), blk, 0, stream>>>(SH, cumdecay);
    inter_kernel<<<dim3(NCH), blk, 0, stream>>>(xBCb, SH, cumdecay, ybuf);
    // 5. ybf = bf16(rmsnorm((y + D*x) * silu(z)))
    norm1_kernel<<<dim3(TOKENS), blk, 0, stream>>>(zxb, xBCb, D_param, ybuf, ybf, norm_w);
    // 6. h = x + ybf @ W_out  (64x128 tiles: 8 x 64 = 512 blocks, 2 blk/CU)
    gemm64_kernel<3><<<dim3(DMODEL / 128, TOKENS / 64), blk, 0, stream>>>(
        ybf, WoutT, hbuf, nullptr, x, TOKENS, DMODEL, DIN);
    // 7. hnbf = bf16(rmsnorm(h))
    norm2_kernel<<<dim3(TOKENS), blk, 0, stream>>>(hbuf, hnbf, rms_w);
    // 8. midbf = bf16(silu(hnbf @ mlp_w1 + b1))  (128^2 KT=64: 32 x 32 = 1024 blocks)
    gemm_bf16_kernel<1, 64><<<dim3(MLP_INNER / 128, TOKENS / 128), blk, 0, stream>>>(
        hnbf, w1T, midbf, mlp_b1, nullptr, TOKENS, MLP_INNER, DMODEL);
    // 9. out = h + midbf @ mlp_w2 + b2  (64x128 tiles: 512 blocks, 2 blk/CU)
    gemm64_kernel<2><<<dim3(DMODEL / 128, TOKENS / 64), blk, 0, stream>>>(
        midbf, w2T, out, mlp_b2, hbuf, TOKENS, DMODEL, MLP_INNER);
}